// Round 1
// baseline (2004.158 us; speedup 1.0000x reference)
//
#include <hip/hip_runtime.h>

// Problem dims (fixed by the reference)
constexpr int EMBED = 1024;
constexpr int NHEAD = 16;
constexpr int HDIM  = 64;
constexpr int BATCH = 2;
constexpr int SEQ   = 2048;
constexpr int MROWS = BATCH * SEQ;   // 4096

// ---------------------------------------------------------------------------
// GEMM: C[M,N] = A[M,K] * W[K,N] + bias[N], M=4096, N=K=1024, fp32.
// 128x128 tile, BK=16, 256 threads, 8x8 per thread.
// gridDim.z selects among 3 (W,bias,C) triples so QKV is one launch.
// ---------------------------------------------------------------------------
__global__ __launch_bounds__(256) void gemm_bias_k(
    const float* __restrict__ A,
    const float* __restrict__ W0, const float* __restrict__ W1, const float* __restrict__ W2,
    const float* __restrict__ B0, const float* __restrict__ B1, const float* __restrict__ B2,
    float* __restrict__ C0, float* __restrict__ C1, float* __restrict__ C2)
{
    constexpr int K = EMBED, N = EMBED;
    const int z = blockIdx.z;
    const float* W  = (z == 0) ? W0 : (z == 1) ? W1 : W2;
    const float* Bv = (z == 0) ? B0 : (z == 1) ? B1 : B2;
    float*       C  = (z == 0) ? C0 : (z == 1) ? C1 : C2;

    // As transposed [k][m]; pad 132 so row base (528B) stays 16B-aligned.
    __shared__ float As[16][132];
    __shared__ float Bs[16][132];

    const int tid = threadIdx.x;
    const int tx = tid & 15, ty = tid >> 4;
    const int row0 = blockIdx.y * 128;
    const int col0 = blockIdx.x * 128;

    float acc[8][8] = {};

    for (int k0 = 0; k0 < K; k0 += 16) {
        // A tile: 128 rows x 16 k  ->  As[k][m]  (512 float4 loads)
        #pragma unroll
        for (int it = 0; it < 2; ++it) {
            int idx = tid + it * 256;          // 0..511
            int r   = idx >> 2;                // 0..127
            int c4  = (idx & 3) * 4;           // 0,4,8,12
            float4 av = *reinterpret_cast<const float4*>(
                &A[(size_t)(row0 + r) * K + k0 + c4]);
            As[c4 + 0][r] = av.x; As[c4 + 1][r] = av.y;
            As[c4 + 2][r] = av.z; As[c4 + 3][r] = av.w;
        }
        // W tile: 16 k x 128 cols -> Bs[k][n]
        #pragma unroll
        for (int it = 0; it < 2; ++it) {
            int idx = tid + it * 256;
            int r   = idx >> 5;                // 0..15
            int c4  = (idx & 31) * 4;          // 0..124
            *reinterpret_cast<float4*>(&Bs[r][c4]) =
                *reinterpret_cast<const float4*>(&W[(size_t)(k0 + r) * N + col0 + c4]);
        }
        __syncthreads();
        #pragma unroll
        for (int k = 0; k < 16; ++k) {
            float a[8], b[8];
            *reinterpret_cast<float4*>(&a[0]) = *reinterpret_cast<const float4*>(&As[k][ty * 8]);
            *reinterpret_cast<float4*>(&a[4]) = *reinterpret_cast<const float4*>(&As[k][ty * 8 + 4]);
            *reinterpret_cast<float4*>(&b[0]) = *reinterpret_cast<const float4*>(&Bs[k][tx * 8]);
            *reinterpret_cast<float4*>(&b[4]) = *reinterpret_cast<const float4*>(&Bs[k][tx * 8 + 4]);
            #pragma unroll
            for (int i = 0; i < 8; ++i)
                #pragma unroll
                for (int j = 0; j < 8; ++j)
                    acc[i][j] += a[i] * b[j];
        }
        __syncthreads();
    }
    #pragma unroll
    for (int i = 0; i < 8; ++i) {
        int r = row0 + ty * 8 + i;
        #pragma unroll
        for (int j = 0; j < 8; j += 4) {
            int c = col0 + tx * 8 + j;
            float4 ov;
            ov.x = acc[i][j + 0] + Bv[c + 0];
            ov.y = acc[i][j + 1] + Bv[c + 1];
            ov.z = acc[i][j + 2] + Bv[c + 2];
            ov.w = acc[i][j + 3] + Bv[c + 3];
            *reinterpret_cast<float4*>(&C[(size_t)r * N + c]) = ov;
        }
    }
}

// ---------------------------------------------------------------------------
// Flash-style attention, fp32. One 64-thread block per (b, h, 64-row Q tile).
// scores = QK^T / HDIM (note: /64, NOT /sqrt(64)), online softmax, O = P V.
// Q,K stored transposed in LDS ([d][row]); P tile aliases the K region
// (K is dead once S is computed) to keep LDS ~49KB -> 3 blocks/CU.
// ---------------------------------------------------------------------------
__global__ __launch_bounds__(64) void attn_k(
    const float* __restrict__ Qg, const float* __restrict__ Kg,
    const float* __restrict__ Vg, float* __restrict__ O)
{
    const int qt  = blockIdx.x;          // 0..31
    const int h   = blockIdx.y;          // 0..15
    const int b   = blockIdx.z;          // 0..1
    const int tid = threadIdx.x;
    const int tx  = tid & 7, ty = tid >> 3;

    __shared__ float Qst[64][64];        // [d][qrow]
    __shared__ float KP[64 * 68];        // Kst: [d*68 + krow]; later Ps: [q*65 + k]
    __shared__ float Vs[64][64];         // [krow][d]

    const size_t base = (size_t)b * SEQ * EMBED + (size_t)h * HDIM;
    const int q0 = qt * 64;

    // load Q tile transposed (4096 floats = 1024 float4)
    #pragma unroll
    for (int it = 0; it < 16; ++it) {
        int idx = tid + it * 64;
        int r   = idx >> 4;              // 0..63
        int c4  = (idx & 15) * 4;
        float4 qv = *reinterpret_cast<const float4*>(
            &Qg[base + (size_t)(q0 + r) * EMBED + c4]);
        Qst[c4 + 0][r] = qv.x; Qst[c4 + 1][r] = qv.y;
        Qst[c4 + 2][r] = qv.z; Qst[c4 + 3][r] = qv.w;
    }

    float m_run[8], l_run[8], oacc[8][8];
    #pragma unroll
    for (int i = 0; i < 8; ++i) {
        m_run[i] = -1e30f; l_run[i] = 0.f;
        #pragma unroll
        for (int j = 0; j < 8; ++j) oacc[i][j] = 0.f;
    }
    const float scale = 1.0f / (float)HDIM;

    for (int t = 0; t < SEQ / 64; ++t) {
        const int k0 = t * 64;
        __syncthreads();   // prev tile consumed (also publishes Qst on t==0)
        #pragma unroll
        for (int it = 0; it < 16; ++it) {
            int idx = tid + it * 64;
            int r   = idx >> 4;
            int c4  = (idx & 15) * 4;
            float4 kv = *reinterpret_cast<const float4*>(
                &Kg[base + (size_t)(k0 + r) * EMBED + c4]);
            KP[(c4 + 0) * 68 + r] = kv.x; KP[(c4 + 1) * 68 + r] = kv.y;
            KP[(c4 + 2) * 68 + r] = kv.z; KP[(c4 + 3) * 68 + r] = kv.w;
            *reinterpret_cast<float4*>(&Vs[r][c4]) =
                *reinterpret_cast<const float4*>(&Vg[base + (size_t)(k0 + r) * EMBED + c4]);
        }
        __syncthreads();

        // S = Q K^T (8x8 per thread)
        float s[8][8] = {};
        #pragma unroll 8
        for (int d = 0; d < 64; ++d) {
            float a[8], bb[8];
            *reinterpret_cast<float4*>(&a[0])  = *reinterpret_cast<const float4*>(&Qst[d][ty * 8]);
            *reinterpret_cast<float4*>(&a[4])  = *reinterpret_cast<const float4*>(&Qst[d][ty * 8 + 4]);
            *reinterpret_cast<float4*>(&bb[0]) = *reinterpret_cast<const float4*>(&KP[d * 68 + tx * 8]);
            *reinterpret_cast<float4*>(&bb[4]) = *reinterpret_cast<const float4*>(&KP[d * 68 + tx * 8 + 4]);
            #pragma unroll
            for (int i = 0; i < 8; ++i)
                #pragma unroll
                for (int j = 0; j < 8; ++j)
                    s[i][j] += a[i] * bb[j];
        }
        __syncthreads();   // all threads done reading Kst before P overwrites it

        // online softmax (rows owned by ty group; reduce across 8 tx lanes)
        #pragma unroll
        for (int i = 0; i < 8; ++i) {
            float mx = -1e30f;
            #pragma unroll
            for (int j = 0; j < 8; ++j) { s[i][j] *= scale; mx = fmaxf(mx, s[i][j]); }
            #pragma unroll
            for (int off = 1; off < 8; off <<= 1) mx = fmaxf(mx, __shfl_xor(mx, off));
            float mnew = fmaxf(m_run[i], mx);
            float corr = __expf(m_run[i] - mnew);
            float psum = 0.f;
            #pragma unroll
            for (int j = 0; j < 8; ++j) { float p = __expf(s[i][j] - mnew); s[i][j] = p; psum += p; }
            #pragma unroll
            for (int off = 1; off < 8; off <<= 1) psum += __shfl_xor(psum, off);
            m_run[i] = mnew;
            l_run[i] = l_run[i] * corr + psum;
            #pragma unroll
            for (int j = 0; j < 8; ++j) oacc[i][j] *= corr;
            #pragma unroll
            for (int j = 0; j < 8; ++j) KP[(ty * 8 + i) * 65 + tx * 8 + j] = s[i][j];
        }
        __syncthreads();

        // O += P V
        #pragma unroll 8
        for (int jp = 0; jp < 64; ++jp) {
            float vv[8], pv[8];
            *reinterpret_cast<float4*>(&vv[0]) = *reinterpret_cast<const float4*>(&Vs[jp][tx * 8]);
            *reinterpret_cast<float4*>(&vv[4]) = *reinterpret_cast<const float4*>(&Vs[jp][tx * 8 + 4]);
            #pragma unroll
            for (int i = 0; i < 8; ++i) pv[i] = KP[(ty * 8 + i) * 65 + jp];
            #pragma unroll
            for (int i = 0; i < 8; ++i)
                #pragma unroll
                for (int j = 0; j < 8; ++j)
                    oacc[i][j] += pv[i] * vv[j];
        }
    }

    #pragma unroll
    for (int i = 0; i < 8; ++i) {
        float inv = 1.0f / l_run[i];
        int r = q0 + ty * 8 + i;
        #pragma unroll
        for (int j = 0; j < 8; j += 4) {
            float4 ov;
            ov.x = oacc[i][j + 0] * inv; ov.y = oacc[i][j + 1] * inv;
            ov.z = oacc[i][j + 2] * inv; ov.w = oacc[i][j + 3] * inv;
            *reinterpret_cast<float4*>(&O[base + (size_t)r * EMBED + tx * 8 + j]) = ov;
        }
    }
}

// ---------------------------------------------------------------------------
extern "C" void kernel_launch(void* const* d_in, const int* in_sizes, int n_in,
                              void* d_out, int out_size, void* d_ws, size_t ws_size,
                              hipStream_t stream)
{
    const float* x  = (const float*)d_in[0];
    const float* Wq = (const float*)d_in[1];
    const float* bq = (const float*)d_in[2];
    const float* Wk = (const float*)d_in[3];
    const float* bk = (const float*)d_in[4];
    const float* Wv = (const float*)d_in[5];
    const float* bv = (const float*)d_in[6];
    const float* Wo = (const float*)d_in[7];
    const float* bo = (const float*)d_in[8];
    float* out = (float*)d_out;

    const size_t elems = (size_t)MROWS * EMBED;   // 4M floats = 16MB
    float* Qb = (float*)d_ws;
    float* Kb = Qb + elems;
    float* Vb = Kb + elems;
    float* Ab = Vb + elems;                       // attention output [M, D]

    // QKV projections (one fused launch, z selects q/k/v)
    dim3 ggrid(EMBED / 128, MROWS / 128, 3);
    gemm_bias_k<<<ggrid, dim3(256), 0, stream>>>(x, Wq, Wk, Wv, bq, bk, bv, Qb, Kb, Vb);

    // attention
    dim3 agrid(SEQ / 64, NHEAD, BATCH);
    attn_k<<<agrid, dim3(64), 0, stream>>>(Qb, Kb, Vb, Ab);

    // output projection
    dim3 ogrid(EMBED / 128, MROWS / 128, 1);
    gemm_bias_k<<<ogrid, dim3(256), 0, stream>>>(Ab, Wo, Wo, Wo, bo, bo, bo, out, out, out);
}

// Round 2
// 980.642 us; speedup vs baseline: 2.0437x; 2.0437x over previous
//
#include <hip/hip_runtime.h>

constexpr int EMBED = 1024;
constexpr int NHEAD = 16;
constexpr int HDIM  = 64;
constexpr int BATCH = 2;
constexpr int SEQ   = 2048;
constexpr int MROWS = BATCH * SEQ;   // 4096

// ---------------------------------------------------------------------------
// GEMM: C[M,N] = A[M,K] * W[K,N] + bias[N], fp32, 128x128 tile, BK=16,
// 256 threads, 8x8/thread. gridDim.z selects among 3 weight/bias/out triples.
// ---------------------------------------------------------------------------
__global__ __launch_bounds__(256) void gemm_bias_k(
    const float* __restrict__ A,
    const float* __restrict__ W0, const float* __restrict__ W1, const float* __restrict__ W2,
    const float* __restrict__ B0, const float* __restrict__ B1, const float* __restrict__ B2,
    float* __restrict__ C0, float* __restrict__ C1, float* __restrict__ C2)
{
    constexpr int K = EMBED, N = EMBED;
    const int z = blockIdx.z;
    const float* W  = (z == 0) ? W0 : (z == 1) ? W1 : W2;
    const float* Bv = (z == 0) ? B0 : (z == 1) ? B1 : B2;
    float*       C  = (z == 0) ? C0 : (z == 1) ? C1 : C2;

    __shared__ float As[16][132];
    __shared__ float Bs[16][132];

    const int tid = threadIdx.x;
    const int tx = tid & 15, ty = tid >> 4;
    const int row0 = blockIdx.y * 128;
    const int col0 = blockIdx.x * 128;

    float acc[8][8] = {};

    for (int k0 = 0; k0 < K; k0 += 16) {
        #pragma unroll
        for (int it = 0; it < 2; ++it) {
            int idx = tid + it * 256;
            int r   = idx >> 2;
            int c4  = (idx & 3) * 4;
            float4 av = *reinterpret_cast<const float4*>(
                &A[(size_t)(row0 + r) * K + k0 + c4]);
            As[c4 + 0][r] = av.x; As[c4 + 1][r] = av.y;
            As[c4 + 2][r] = av.z; As[c4 + 3][r] = av.w;
        }
        #pragma unroll
        for (int it = 0; it < 2; ++it) {
            int idx = tid + it * 256;
            int r   = idx >> 5;
            int c4  = (idx & 31) * 4;
            *reinterpret_cast<float4*>(&Bs[r][c4]) =
                *reinterpret_cast<const float4*>(&W[(size_t)(k0 + r) * N + col0 + c4]);
        }
        __syncthreads();
        #pragma unroll
        for (int k = 0; k < 16; ++k) {
            float a[8], b[8];
            *reinterpret_cast<float4*>(&a[0]) = *reinterpret_cast<const float4*>(&As[k][ty * 8]);
            *reinterpret_cast<float4*>(&a[4]) = *reinterpret_cast<const float4*>(&As[k][ty * 8 + 4]);
            *reinterpret_cast<float4*>(&b[0]) = *reinterpret_cast<const float4*>(&Bs[k][tx * 8]);
            *reinterpret_cast<float4*>(&b[4]) = *reinterpret_cast<const float4*>(&Bs[k][tx * 8 + 4]);
            #pragma unroll
            for (int i = 0; i < 8; ++i)
                #pragma unroll
                for (int j = 0; j < 8; ++j)
                    acc[i][j] += a[i] * b[j];
        }
        __syncthreads();
    }
    #pragma unroll
    for (int i = 0; i < 8; ++i) {
        int r = row0 + ty * 8 + i;
        #pragma unroll
        for (int j = 0; j < 8; j += 4) {
            int c = col0 + tx * 8 + j;
            float4 ov;
            ov.x = acc[i][j + 0] + Bv[c + 0];
            ov.y = acc[i][j + 1] + Bv[c + 1];
            ov.z = acc[i][j + 2] + Bv[c + 2];
            ov.w = acc[i][j + 3] + Bv[c + 3];
            *reinterpret_cast<float4*>(&C[(size_t)r * N + c]) = ov;
        }
    }
}

// ---------------------------------------------------------------------------
// Flash attention v2, fp32. 128-thread blocks (2 waves), Q-tile 128,
// K-tile 64, 8x8 per thread in both phases (1.0 LDS-byte/FMA).
// LDS 80KB: Q^T 32K | P 32K (K^T aliased, dead after S) | V 16K
//   -> 2 blocks/CU. XOR-swizzled float4 units kill cross-row bank conflicts.
// scores = QK^T / 64 (reference divides by head_dim), online softmax.
// ---------------------------------------------------------------------------
__global__ __launch_bounds__(128) void attn_k(
    const float* __restrict__ Qg, const float* __restrict__ Kg,
    const float* __restrict__ Vg, float* __restrict__ O)
{
    // bijective XCD swizzle: 512 blocks -> chunks of 64 per XCD, so all 16
    // q-tiles of a head (plus 3 neighbor heads) share one XCD L2.
    const int bid = blockIdx.x;
    const int swz = (bid & 7) * 64 + (bid >> 3);
    const int qt = swz & 15, h = (swz >> 4) & 15, b = swz >> 8;

    __shared__ float Qs[64 * 128];   // [d][qrow], float4-unit swizzled by d&7
    __shared__ float PK[128 * 64];   // P [qrow][k] swz by qrow>>3; K^T aliased (first 16KB): [d][krow] swz by d&7
    __shared__ float Vs[64 * 64];    // [krow][d] natural

    const int tid = threadIdx.x;
    const int tx = tid & 7, ty = tid >> 3;   // tx: 8 k-col groups, ty: 16 q-row groups
    const int tyl = ty & 7;
    const size_t base = (size_t)b * SEQ * EMBED + (size_t)h * HDIM;
    const int q0 = qt * 128;

    // ---- load Q tile transposed + swizzled (one-time) ----
    #pragma unroll
    for (int it = 0; it < 16; ++it) {
        int idx = tid + it * 128;
        int r = idx >> 4, c4 = (idx & 15) * 4;
        float4 qv = *reinterpret_cast<const float4*>(
            &Qg[base + (size_t)(q0 + r) * EMBED + c4]);
        int u = r >> 2, rl = r & 3;
        float qe[4] = {qv.x, qv.y, qv.z, qv.w};
        #pragma unroll
        for (int e = 0; e < 4; ++e) {
            int d = c4 + e;
            int up = (u & 24) | ((u ^ (d & 7)) & 7);
            Qs[d * 128 + up * 4 + rl] = qe[e];
        }
    }

    float m_run[8], l_run[8], oacc[8][8];
    #pragma unroll
    for (int i = 0; i < 8; ++i) {
        m_run[i] = -1e30f; l_run[i] = 0.f;
        #pragma unroll
        for (int j = 0; j < 8; ++j) oacc[i][j] = 0.f;
    }
    const float scale = 1.0f / (float)HDIM;

    for (int t = 0; t < SEQ / 64; ++t) {
        const int k0 = t * 64;
        __syncthreads();   // prev PV done reading PK/Vs (also covers Q publish on t==0)

        // ---- stage K^T (swizzled, into PK) and V (natural) ----
        #pragma unroll
        for (int it = 0; it < 8; ++it) {
            int idx = tid + it * 128;
            int r = idx >> 4, c4 = (idx & 15) * 4;
            float4 kv = *reinterpret_cast<const float4*>(
                &Kg[base + (size_t)(k0 + r) * EMBED + c4]);
            float4 vv = *reinterpret_cast<const float4*>(
                &Vg[base + (size_t)(k0 + r) * EMBED + c4]);
            int u = r >> 2, rl = r & 3;
            float ke[4] = {kv.x, kv.y, kv.z, kv.w};
            #pragma unroll
            for (int e = 0; e < 4; ++e) {
                int d = c4 + e;
                int up = (u & 8) | ((u ^ (d & 7)) & 7);
                PK[d * 64 + up * 4 + rl] = ke[e];
            }
            *reinterpret_cast<float4*>(&Vs[r * 64 + c4]) = vv;
        }
        __syncthreads();

        // ---- S = Q K^T, 8x8 per thread ----
        float s[8][8] = {};
        for (int dblk = 0; dblk < 8; ++dblk) {
            #pragma unroll
            for (int dd = 0; dd < 8; ++dd) {
                int d = dblk * 8 + dd;
                float a[8], bb[8];
                int ua0 = ((2 * ty) & 24)     | (((2 * ty) ^ dd) & 7);
                int ua1 = ((2 * ty + 1) & 24) | (((2 * ty + 1) ^ dd) & 7);
                *reinterpret_cast<float4*>(&a[0]) = *reinterpret_cast<const float4*>(&Qs[d * 128 + ua0 * 4]);
                *reinterpret_cast<float4*>(&a[4]) = *reinterpret_cast<const float4*>(&Qs[d * 128 + ua1 * 4]);
                int ub0 = ((2 * tx) & 8)     | (((2 * tx) ^ dd) & 7);
                int ub1 = ((2 * tx + 1) & 8) | (((2 * tx + 1) ^ dd) & 7);
                *reinterpret_cast<float4*>(&bb[0]) = *reinterpret_cast<const float4*>(&PK[d * 64 + ub0 * 4]);
                *reinterpret_cast<float4*>(&bb[4]) = *reinterpret_cast<const float4*>(&PK[d * 64 + ub1 * 4]);
                #pragma unroll
                for (int i = 0; i < 8; ++i)
                    #pragma unroll
                    for (int j = 0; j < 8; ++j)
                        s[i][j] += a[i] * bb[j];
            }
        }
        __syncthreads();   // all K reads done before P overwrites the region

        // ---- online softmax (rows ty*8+i; reduce across 8 tx lanes) ----
        #pragma unroll
        for (int i = 0; i < 8; ++i) {
            float mx = -1e30f;
            #pragma unroll
            for (int j = 0; j < 8; ++j) { s[i][j] *= scale; mx = fmaxf(mx, s[i][j]); }
            #pragma unroll
            for (int off = 1; off < 8; off <<= 1) mx = fmaxf(mx, __shfl_xor(mx, off));
            float mnew = fmaxf(m_run[i], mx);
            float corr = __expf(m_run[i] - mnew);
            float psum = 0.f;
            #pragma unroll
            for (int j = 0; j < 8; ++j) { float p = __expf(s[i][j] - mnew); s[i][j] = p; psum += p; }
            #pragma unroll
            for (int off = 1; off < 8; off <<= 1) psum += __shfl_xor(psum, off);
            m_run[i] = mnew;
            l_run[i] = l_run[i] * corr + psum;
            #pragma unroll
            for (int j = 0; j < 8; ++j) oacc[i][j] *= corr;
            // P write, swizzled by qrow>>3 (= ty)
            #pragma unroll
            for (int j4 = 0; j4 < 2; ++j4) {
                int u  = 2 * tx + j4;
                int up = (u & 8) | ((u ^ tyl) & 7);
                float4 pw;
                pw.x = s[i][j4 * 4 + 0]; pw.y = s[i][j4 * 4 + 1];
                pw.z = s[i][j4 * 4 + 2]; pw.w = s[i][j4 * 4 + 3];
                *reinterpret_cast<float4*>(&PK[(ty * 8 + i) * 64 + up * 4]) = pw;
            }
        }
        __syncthreads();

        // ---- O += P V, 8x8 per thread, 4 k-steps per iteration ----
        for (int jp4 = 0; jp4 < 16; ++jp4) {
            int up = (jp4 & 8) | ((jp4 ^ tyl) & 7);
            float p4[8][4];
            #pragma unroll
            for (int i = 0; i < 8; ++i)
                *reinterpret_cast<float4*>(&p4[i][0]) =
                    *reinterpret_cast<const float4*>(&PK[(ty * 8 + i) * 64 + up * 4]);
            float vv[4][8];
            #pragma unroll
            for (int e = 0; e < 4; ++e) {
                *reinterpret_cast<float4*>(&vv[e][0]) =
                    *reinterpret_cast<const float4*>(&Vs[(jp4 * 4 + e) * 64 + tx * 8]);
                *reinterpret_cast<float4*>(&vv[e][4]) =
                    *reinterpret_cast<const float4*>(&Vs[(jp4 * 4 + e) * 64 + tx * 8 + 4]);
            }
            #pragma unroll
            for (int e = 0; e < 4; ++e)
                #pragma unroll
                for (int i = 0; i < 8; ++i)
                    #pragma unroll
                    for (int j = 0; j < 8; ++j)
                        oacc[i][j] += p4[i][e] * vv[e][j];
        }
    }

    // ---- epilogue: normalize and store ----
    #pragma unroll
    for (int i = 0; i < 8; ++i) {
        float inv = 1.0f / l_run[i];
        int r = q0 + ty * 8 + i;
        #pragma unroll
        for (int j4 = 0; j4 < 2; ++j4) {
            float4 ov;
            ov.x = oacc[i][j4 * 4 + 0] * inv; ov.y = oacc[i][j4 * 4 + 1] * inv;
            ov.z = oacc[i][j4 * 4 + 2] * inv; ov.w = oacc[i][j4 * 4 + 3] * inv;
            *reinterpret_cast<float4*>(&O[base + (size_t)r * EMBED + tx * 8 + j4 * 4]) = ov;
        }
    }
}

// ---------------------------------------------------------------------------
extern "C" void kernel_launch(void* const* d_in, const int* in_sizes, int n_in,
                              void* d_out, int out_size, void* d_ws, size_t ws_size,
                              hipStream_t stream)
{
    const float* x  = (const float*)d_in[0];
    const float* Wq = (const float*)d_in[1];
    const float* bq = (const float*)d_in[2];
    const float* Wk = (const float*)d_in[3];
    const float* bk = (const float*)d_in[4];
    const float* Wv = (const float*)d_in[5];
    const float* bv = (const float*)d_in[6];
    const float* Wo = (const float*)d_in[7];
    const float* bo = (const float*)d_in[8];
    float* out = (float*)d_out;

    const size_t elems = (size_t)MROWS * EMBED;
    float* Qb = (float*)d_ws;
    float* Kb = Qb + elems;
    float* Vb = Kb + elems;
    float* Ab = Vb + elems;

    dim3 ggrid(EMBED / 128, MROWS / 128, 3);
    gemm_bias_k<<<ggrid, dim3(256), 0, stream>>>(x, Wq, Wk, Wv, bq, bk, bv, Qb, Kb, Vb);

    attn_k<<<dim3(512), dim3(128), 0, stream>>>(Qb, Kb, Vb, Ab);

    dim3 ogrid(EMBED / 128, MROWS / 128, 1);
    gemm_bias_k<<<ogrid, dim3(256), 0, stream>>>(Ab, Wo, Wo, Wo, bo, bo, bo, out, out, out);
}

// Round 3
// 791.476 us; speedup vs baseline: 2.5322x; 1.2390x over previous
//
#include <hip/hip_runtime.h>

constexpr int EMBED = 1024;
constexpr int NHEAD = 16;
constexpr int HDIM  = 64;
constexpr int BATCH = 2;
constexpr int SEQ   = 2048;
constexpr int MROWS = BATCH * SEQ;   // 4096
constexpr int NKB   = EMBED / 32;    // 32 k-blocks of 32

typedef __attribute__((ext_vector_type(8)))  short          bf8;   // 8 bf16 (4 VGPR)
typedef __attribute__((ext_vector_type(8)))  unsigned short us8;
typedef __attribute__((ext_vector_type(16))) float          f32x16;

__device__ __forceinline__ unsigned short f2bf(float f) {  // RNE fp32->bf16
  unsigned u = __float_as_uint(f);
  u += 0x7fffu + ((u >> 16) & 1u);
  return (unsigned short)(u >> 16);
}
__device__ __forceinline__ float bf2f(unsigned short h) {
  return __uint_as_float((unsigned)h << 16);
}
__device__ __forceinline__ void async16(const void* g, void* l) {
  __builtin_amdgcn_global_load_lds(
      (const __attribute__((address_space(1))) unsigned int*)g,
      (__attribute__((address_space(3))) unsigned int*)l, 16, 0, 0);
}

// ---------------------------------------------------------------------------
// Pack a row-major fp32 [R][1024] matrix into split-bf16 256B-unit layout:
// unit u = row-pair, per (u, kblk t): 16 slots of 16B; slot s holds
// c = s ^ (u&15) -> {par = c>>3, plane = (c>>2)&1, kb8 = c&3}:
// 8 bf16 of plane(hi/lo) of row 2u+par, k = t*32 + kb8*8 .. +8.
// Flat addr = sid*16 with sid = u*512 + t*16 + s.  This layout IS the LDS
// image, so GEMM staging is a linear global_load_lds.
// ---------------------------------------------------------------------------
__global__ __launch_bounds__(256) void pack_rows_k(
    const float* __restrict__ in, char* __restrict__ outp, int nslots)
{
  int sid = blockIdx.x * 256 + threadIdx.x;
  if (sid >= nslots) return;
  int s = sid & 15;
  int t = (sid >> 4) & (NKB - 1);
  int u = sid >> 9;
  int c = s ^ (u & 15);
  int par = c >> 3, pl = (c >> 2) & 1, kb8 = c & 3;
  const float* src = in + (size_t)(2 * u + par) * EMBED + t * 32 + kb8 * 8;
  us8 o;
  #pragma unroll
  for (int e = 0; e < 8; ++e) {
    float f = src[e];
    unsigned short h = f2bf(f);
    o[e] = pl ? f2bf(f - bf2f(h)) : h;
  }
  *(us8*)(outp + ((size_t)sid << 4)) = o;
}

// ---------------------------------------------------------------------------
// Split-bf16 MFMA GEMM: C[4096][1024] = A(packed) * W(fp32 [K][N]) + bias.
// 128x128 tile, 4 waves (2x2), per-wave 2x2 frags of 32x32x16, 3-term split.
// A staged via linear global_load_lds; W split/transposed in-kernel.
// nz=3 -> z in {0,1,2} selects (W,bias,C); nz=1 -> single output.
// ---------------------------------------------------------------------------
__global__ __launch_bounds__(256) void gemm_mfma_k(
    const char* __restrict__ Apack,
    const float* __restrict__ W0, const float* __restrict__ W1, const float* __restrict__ W2,
    const float* __restrict__ B0, const float* __restrict__ B1, const float* __restrict__ B2,
    float* __restrict__ C0, float* __restrict__ C1, float* __restrict__ C2,
    int nz)
{
  constexpr int N = EMBED;
  __shared__ __align__(16) char Asm[16384];
  __shared__ __align__(16) char Wsm[16384];

  const int tid  = threadIdx.x;
  const int lane = tid & 63;
  const int wid  = tid >> 6;
  const int wr   = wid >> 1, wc = wid & 1;
  const int ln31 = lane & 31, lhalf = lane >> 5;

  // XCD-bijective swizzle + (rowpanel, z, colblock) decode
  const int nwg = gridDim.x;            // 768 (QKV) or 256 (out-proj); %8==0
  const int per = nwg >> 3;
  const int bid = blockIdx.x;
  const int swz = (bid & 7) * per + (bid >> 3);
  const int zc  = nz << 3;
  const int rp  = swz / zc;
  const int sub = swz - rp * zc;
  const int z   = sub >> 3, cb = sub & 7;

  const float* Wp = (z == 0) ? W0 : (z == 1) ? W1 : W2;
  const float* Bv = (z == 0) ? B0 : (z == 1) ? B1 : B2;
  float*       C  = (z == 0) ? C0 : (z == 1) ? C1 : C2;

  const int M0 = rp * 128, N0 = cb * 128;
  const int U0 = M0 >> 1;

  // hoisted W-slot decode (4 slots per thread, t-invariant)
  int wu[4], wss[4], wpl[4];
  const float* wsrc[4];
  #pragma unroll
  for (int w = 0; w < 4; ++w) {
    int sid = tid + (w << 8);
    int u = sid >> 4, s = sid & 15;
    int c = s ^ (u & 15);
    wu[w] = u; wss[w] = s; wpl[w] = (c >> 2) & 1;
    int par = c >> 3, kb8 = c & 3;
    wsrc[w] = Wp + (size_t)(kb8 * 8) * N + (N0 + 2 * u + par);
  }

  // hoisted A staging addresses
  const char* abase[4];
  char* aldst[4];
  #pragma unroll
  for (int i = 0; i < 4; ++i) {
    int ul = i * 16 + (tid >> 4);
    abase[i] = Apack + (((size_t)(U0 + ul) * NKB) << 8) + ((tid & 15) << 4);
    aldst[i] = &Asm[i * 4096 + (tid >> 6) * 1024];   // wave-uniform base
  }

  f32x16 acc[2][2];
  #pragma unroll
  for (int mi = 0; mi < 2; ++mi)
    #pragma unroll
    for (int ni = 0; ni < 2; ++ni)
      #pragma unroll
      for (int q = 0; q < 16; ++q) acc[mi][ni][q] = 0.f;

  for (int t = 0; t < NKB; ++t) {
    // A tile: async global->LDS (layout already packed+swizzled)
    #pragma unroll
    for (int i = 0; i < 4; ++i)
      async16(abase[i] + ((size_t)t << 8), aldst[i]);

    // W tile: coalesced-across-lanes strided loads, split, linear ds_write
    #pragma unroll
    for (int w = 0; w < 4; ++w) {
      const float* src = wsrc[w] + (size_t)(t * 32) * N;
      float v[8];
      #pragma unroll
      for (int e = 0; e < 8; ++e) v[e] = src[(size_t)e * N];
      us8 o;
      #pragma unroll
      for (int e = 0; e < 8; ++e) {
        unsigned short h = f2bf(v[e]);
        o[e] = wpl[w] ? f2bf(v[e] - bf2f(h)) : h;
      }
      *(us8*)(Wsm + wu[w] * 256 + wss[w] * 16) = o;
    }
    __syncthreads();   // drains vmcnt (gload_lds) + lgkm (ds_write) + barrier

    #pragma unroll
    for (int h = 0; h < 2; ++h) {
      const int kb = h * 2 + lhalf;
      bf8 aH[2], aL[2], bH[2], bL[2];
      #pragma unroll
      for (int mi = 0; mi < 2; ++mi) {
        int m = wr * 64 + mi * 32 + ln31;
        int u = m >> 1;
        int sH = (((m & 1) << 3) | kb) ^ (u & 15);
        aH[mi] = *(const bf8*)(Asm + u * 256 + sH * 16);
        aL[mi] = *(const bf8*)(Asm + u * 256 + (sH ^ 4) * 16);
      }
      #pragma unroll
      for (int ni = 0; ni < 2; ++ni) {
        int n = wc * 64 + ni * 32 + ln31;
        int u = n >> 1;
        int sH = (((n & 1) << 3) | kb) ^ (u & 15);
        bH[ni] = *(const bf8*)(Wsm + u * 256 + sH * 16);
        bL[ni] = *(const bf8*)(Wsm + u * 256 + (sH ^ 4) * 16);
      }
      #pragma unroll
      for (int mi = 0; mi < 2; ++mi)
        #pragma unroll
        for (int ni = 0; ni < 2; ++ni) {
          acc[mi][ni] = __builtin_amdgcn_mfma_f32_32x32x16_bf16(aH[mi], bH[ni], acc[mi][ni], 0, 0, 0);
          acc[mi][ni] = __builtin_amdgcn_mfma_f32_32x32x16_bf16(aH[mi], bL[ni], acc[mi][ni], 0, 0, 0);
          acc[mi][ni] = __builtin_amdgcn_mfma_f32_32x32x16_bf16(aL[mi], bH[ni], acc[mi][ni], 0, 0, 0);
        }
    }
    __syncthreads();
  }

  // epilogue: C/D layout col = lane&31, row = (r&3) + 8*(r>>2) + 4*(lane>>5)
  #pragma unroll
  for (int ni = 0; ni < 2; ++ni) {
    int col = N0 + wc * 64 + ni * 32 + ln31;
    float bb = Bv[col];
    #pragma unroll
    for (int mi = 0; mi < 2; ++mi) {
      #pragma unroll
      for (int r = 0; r < 16; ++r) {
        int row = M0 + wr * 64 + mi * 32 + (r & 3) + ((r >> 2) << 3) + (lhalf << 2);
        C[(size_t)row * N + col] = acc[mi][ni][r] + bb;
      }
    }
  }
}

// ---------------------------------------------------------------------------
// Flash attention (unchanged compute from round 2), fp32, 128 threads.
// Epilogue now writes the split-bf16 packed layout directly (input for the
// MFMA output projection).
// ---------------------------------------------------------------------------
__global__ __launch_bounds__(128) void attn_k(
    const float* __restrict__ Qg, const float* __restrict__ Kg,
    const float* __restrict__ Vg, char* __restrict__ A2)
{
  const int bid = blockIdx.x;
  const int swz = (bid & 7) * 64 + (bid >> 3);
  const int qt = swz & 15, h = (swz >> 4) & 15, b = swz >> 8;

  __shared__ float Qs[64 * 128];
  __shared__ float PK[128 * 64];
  __shared__ float Vs[64 * 64];

  const int tid = threadIdx.x;
  const int tx = tid & 7, ty = tid >> 3;
  const int tyl = ty & 7;
  const size_t base = (size_t)b * SEQ * EMBED + (size_t)h * HDIM;
  const int q0 = qt * 128;

  #pragma unroll
  for (int it = 0; it < 16; ++it) {
    int idx = tid + it * 128;
    int r = idx >> 4, c4 = (idx & 15) * 4;
    float4 qv = *reinterpret_cast<const float4*>(
        &Qg[base + (size_t)(q0 + r) * EMBED + c4]);
    int u = r >> 2, rl = r & 3;
    float qe[4] = {qv.x, qv.y, qv.z, qv.w};
    #pragma unroll
    for (int e = 0; e < 4; ++e) {
      int d = c4 + e;
      int up = (u & 24) | ((u ^ (d & 7)) & 7);
      Qs[d * 128 + up * 4 + rl] = qe[e];
    }
  }

  float m_run[8], l_run[8], oacc[8][8];
  #pragma unroll
  for (int i = 0; i < 8; ++i) {
    m_run[i] = -1e30f; l_run[i] = 0.f;
    #pragma unroll
    for (int j = 0; j < 8; ++j) oacc[i][j] = 0.f;
  }
  const float scale = 1.0f / (float)HDIM;

  for (int t = 0; t < SEQ / 64; ++t) {
    const int k0 = t * 64;
    __syncthreads();
    #pragma unroll
    for (int it = 0; it < 8; ++it) {
      int idx = tid + it * 128;
      int r = idx >> 4, c4 = (idx & 15) * 4;
      float4 kv = *reinterpret_cast<const float4*>(
          &Kg[base + (size_t)(k0 + r) * EMBED + c4]);
      float4 vv = *reinterpret_cast<const float4*>(
          &Vg[base + (size_t)(k0 + r) * EMBED + c4]);
      int u = r >> 2, rl = r & 3;
      float ke[4] = {kv.x, kv.y, kv.z, kv.w};
      #pragma unroll
      for (int e = 0; e < 4; ++e) {
        int d = c4 + e;
        int up = (u & 8) | ((u ^ (d & 7)) & 7);
        PK[d * 64 + up * 4 + rl] = ke[e];
      }
      *reinterpret_cast<float4*>(&Vs[r * 64 + c4]) = vv;
    }
    __syncthreads();

    float s[8][8] = {};
    for (int dblk = 0; dblk < 8; ++dblk) {
      #pragma unroll
      for (int dd = 0; dd < 8; ++dd) {
        int d = dblk * 8 + dd;
        float a[8], bb[8];
        int ua0 = ((2 * ty) & 24)     | (((2 * ty) ^ dd) & 7);
        int ua1 = ((2 * ty + 1) & 24) | (((2 * ty + 1) ^ dd) & 7);
        *reinterpret_cast<float4*>(&a[0]) = *reinterpret_cast<const float4*>(&Qs[d * 128 + ua0 * 4]);
        *reinterpret_cast<float4*>(&a[4]) = *reinterpret_cast<const float4*>(&Qs[d * 128 + ua1 * 4]);
        int ub0 = ((2 * tx) & 8)     | (((2 * tx) ^ dd) & 7);
        int ub1 = ((2 * tx + 1) & 8) | (((2 * tx + 1) ^ dd) & 7);
        *reinterpret_cast<float4*>(&bb[0]) = *reinterpret_cast<const float4*>(&PK[d * 64 + ub0 * 4]);
        *reinterpret_cast<float4*>(&bb[4]) = *reinterpret_cast<const float4*>(&PK[d * 64 + ub1 * 4]);
        #pragma unroll
        for (int i = 0; i < 8; ++i)
          #pragma unroll
          for (int j = 0; j < 8; ++j)
            s[i][j] += a[i] * bb[j];
      }
    }
    __syncthreads();

    #pragma unroll
    for (int i = 0; i < 8; ++i) {
      float mx = -1e30f;
      #pragma unroll
      for (int j = 0; j < 8; ++j) { s[i][j] *= scale; mx = fmaxf(mx, s[i][j]); }
      #pragma unroll
      for (int off = 1; off < 8; off <<= 1) mx = fmaxf(mx, __shfl_xor(mx, off));
      float mnew = fmaxf(m_run[i], mx);
      float corr = __expf(m_run[i] - mnew);
      float psum = 0.f;
      #pragma unroll
      for (int j = 0; j < 8; ++j) { float p = __expf(s[i][j] - mnew); s[i][j] = p; psum += p; }
      #pragma unroll
      for (int off = 1; off < 8; off <<= 1) psum += __shfl_xor(psum, off);
      m_run[i] = mnew;
      l_run[i] = l_run[i] * corr + psum;
      #pragma unroll
      for (int j = 0; j < 8; ++j) oacc[i][j] *= corr;
      #pragma unroll
      for (int j4 = 0; j4 < 2; ++j4) {
        int u  = 2 * tx + j4;
        int up = (u & 8) | ((u ^ tyl) & 7);
        float4 pw;
        pw.x = s[i][j4 * 4 + 0]; pw.y = s[i][j4 * 4 + 1];
        pw.z = s[i][j4 * 4 + 2]; pw.w = s[i][j4 * 4 + 3];
        *reinterpret_cast<float4*>(&PK[(ty * 8 + i) * 64 + up * 4]) = pw;
      }
    }
    __syncthreads();

    for (int jp4 = 0; jp4 < 16; ++jp4) {
      int up = (jp4 & 8) | ((jp4 ^ tyl) & 7);
      float p4[8][4];
      #pragma unroll
      for (int i = 0; i < 8; ++i)
        *reinterpret_cast<float4*>(&p4[i][0]) =
            *reinterpret_cast<const float4*>(&PK[(ty * 8 + i) * 64 + up * 4]);
      float vv[4][8];
      #pragma unroll
      for (int e = 0; e < 4; ++e) {
        *reinterpret_cast<float4*>(&vv[e][0]) =
            *reinterpret_cast<const float4*>(&Vs[(jp4 * 4 + e) * 64 + tx * 8]);
        *reinterpret_cast<float4*>(&vv[e][4]) =
            *reinterpret_cast<const float4*>(&Vs[(jp4 * 4 + e) * 64 + tx * 8 + 4]);
      }
      #pragma unroll
      for (int e = 0; e < 4; ++e)
        #pragma unroll
        for (int i = 0; i < 8; ++i)
          #pragma unroll
          for (int j = 0; j < 8; ++j)
            oacc[i][j] += p4[i][e] * vv[e][j];
    }
  }

  // epilogue: write split-bf16 packed layout (hi & lo 16B slots per row)
  const int gk  = h * 64 + tx * 8;
  const int tkb = gk >> 5;
  const int kb8 = (gk >> 3) & 3;
  #pragma unroll
  for (int i = 0; i < 8; ++i) {
    float inv = 1.0f / l_run[i];
    int row = b * SEQ + q0 + ty * 8 + i;
    int u = row >> 1, par = row & 1;
    us8 hi, lo;
    #pragma unroll
    for (int j = 0; j < 8; ++j) {
      float f = oacc[i][j] * inv;
      unsigned short h8 = f2bf(f);
      hi[j] = h8;
      lo[j] = f2bf(f - bf2f(h8));
    }
    size_t ub = (size_t)(u * NKB + tkb) << 8;
    int sH = ((par << 3) | kb8) ^ (u & 15);
    *(us8*)(A2 + ub + sH * 16) = hi;
    *(us8*)(A2 + ub + (sH ^ 4) * 16) = lo;
  }
}

// ---------------------------------------------------------------------------
extern "C" void kernel_launch(void* const* d_in, const int* in_sizes, int n_in,
                              void* d_out, int out_size, void* d_ws, size_t ws_size,
                              hipStream_t stream)
{
  const float* x  = (const float*)d_in[0];
  const float* Wq = (const float*)d_in[1];
  const float* bq = (const float*)d_in[2];
  const float* Wk = (const float*)d_in[3];
  const float* bk = (const float*)d_in[4];
  const float* Wv = (const float*)d_in[5];
  const float* bv = (const float*)d_in[6];
  const float* Wo = (const float*)d_in[7];
  const float* bo = (const float*)d_in[8];
  float* out = (float*)d_out;

  char* wsb = (char*)d_ws;
  float* Qb = (float*)(wsb);
  float* Kb = (float*)(wsb + ((size_t)16 << 20));
  float* Vb = (float*)(wsb + ((size_t)32 << 20));
  char*  R  = wsb + ((size_t)48 << 20);   // Xpack, later A2pack (16MB)

  const int nslots = (MROWS / 2) * NKB * 16;   // 1,048,576
  pack_rows_k<<<dim3(nslots / 256), dim3(256), 0, stream>>>(x, R, nslots);

  gemm_mfma_k<<<dim3(768), dim3(256), 0, stream>>>(
      R, Wq, Wk, Wv, bq, bk, bv, Qb, Kb, Vb, 3);

  attn_k<<<dim3(512), dim3(128), 0, stream>>>(Qb, Kb, Vb, R);

  gemm_mfma_k<<<dim3(256), dim3(256), 0, stream>>>(
      R, Wo, Wo, Wo, bo, bo, bo, out, out, out, 1);
}

// Round 4
// 338.678 us; speedup vs baseline: 5.9176x; 2.3370x over previous
//
#include <hip/hip_runtime.h>

constexpr int EMBED = 1024;
constexpr int NHEAD = 16;
constexpr int HDIM  = 64;
constexpr int BATCH = 2;
constexpr int SEQ   = 2048;
constexpr int MROWS = BATCH * SEQ;   // 4096
constexpr int NKB   = EMBED / 32;    // 32 k-blocks of 32

typedef __attribute__((ext_vector_type(8)))  short          bf8;   // 8 bf16 (4 VGPR)
typedef __attribute__((ext_vector_type(8)))  unsigned short us8;
typedef __attribute__((ext_vector_type(16))) float          f32x16;

__device__ __forceinline__ unsigned short f2bf(float f) {  // RNE fp32->bf16
  unsigned u = __float_as_uint(f);
  u += 0x7fffu + ((u >> 16) & 1u);
  return (unsigned short)(u >> 16);
}
__device__ __forceinline__ float bf2f(unsigned short h) {
  return __uint_as_float((unsigned)h << 16);
}
__device__ __forceinline__ void async16(const void* g, void* l) {
  __builtin_amdgcn_global_load_lds(
      (const __attribute__((address_space(1))) unsigned int*)g,
      (__attribute__((address_space(3))) unsigned int*)l, 16, 0, 0);
}

// ---------------------------------------------------------------------------
// Pack a row-major fp32 [R][1024] matrix into split-bf16 256B-unit layout:
// unit u = row-pair; slot s holds c = s ^ (u&15) -> {par=c>>3, pl=(c>>2)&1,
// kb8=c&3}: 8 bf16 of plane(hi/lo) of row 2u+par, k = t*32+kb8*8..+8.
// ---------------------------------------------------------------------------
__global__ __launch_bounds__(256) void pack_rows_k(
    const float* __restrict__ in, char* __restrict__ outp, int nslots)
{
  int sid = blockIdx.x * 256 + threadIdx.x;
  if (sid >= nslots) return;
  int s = sid & 15;
  int t = (sid >> 4) & (NKB - 1);
  int u = sid >> 9;
  int c = s ^ (u & 15);
  int par = c >> 3, pl = (c >> 2) & 1, kb8 = c & 3;
  const float* src = in + (size_t)(2 * u + par) * EMBED + t * 32 + kb8 * 8;
  us8 o;
  #pragma unroll
  for (int e = 0; e < 8; ++e) {
    float f = src[e];
    unsigned short h = f2bf(f);
    o[e] = pl ? f2bf(f - bf2f(h)) : h;
  }
  *(us8*)(outp + ((size_t)sid << 4)) = o;
}

// ---------------------------------------------------------------------------
// Split-bf16 MFMA GEMM: C[4096][1024] = A(packed) * W(fp32 [K][N]) + bias.
// ---------------------------------------------------------------------------
__global__ __launch_bounds__(256) void gemm_mfma_k(
    const char* __restrict__ Apack,
    const float* __restrict__ W0, const float* __restrict__ W1, const float* __restrict__ W2,
    const float* __restrict__ B0, const float* __restrict__ B1, const float* __restrict__ B2,
    float* __restrict__ C0, float* __restrict__ C1, float* __restrict__ C2,
    int nz)
{
  constexpr int N = EMBED;
  __shared__ __align__(16) char Asm[16384];
  __shared__ __align__(16) char Wsm[16384];

  const int tid  = threadIdx.x;
  const int lane = tid & 63;
  const int wid  = tid >> 6;
  const int wr   = wid >> 1, wc = wid & 1;
  const int ln31 = lane & 31, lhalf = lane >> 5;

  const int nwg = gridDim.x;
  const int per = nwg >> 3;
  const int bid = blockIdx.x;
  const int swz = (bid & 7) * per + (bid >> 3);
  const int zc  = nz << 3;
  const int rp  = swz / zc;
  const int sub = swz - rp * zc;
  const int z   = sub >> 3, cb = sub & 7;

  const float* Wp = (z == 0) ? W0 : (z == 1) ? W1 : W2;
  const float* Bv = (z == 0) ? B0 : (z == 1) ? B1 : B2;
  float*       C  = (z == 0) ? C0 : (z == 1) ? C1 : C2;

  const int M0 = rp * 128, N0 = cb * 128;
  const int U0 = M0 >> 1;

  int wu[4], wss[4], wpl[4];
  const float* wsrc[4];
  #pragma unroll
  for (int w = 0; w < 4; ++w) {
    int sid = tid + (w << 8);
    int u = sid >> 4, s = sid & 15;
    int c = s ^ (u & 15);
    wu[w] = u; wss[w] = s; wpl[w] = (c >> 2) & 1;
    int par = c >> 3, kb8 = c & 3;
    wsrc[w] = Wp + (size_t)(kb8 * 8) * N + (N0 + 2 * u + par);
  }

  const char* abase[4];
  char* aldst[4];
  #pragma unroll
  for (int i = 0; i < 4; ++i) {
    int ul = i * 16 + (tid >> 4);
    abase[i] = Apack + (((size_t)(U0 + ul) * NKB) << 8) + ((tid & 15) << 4);
    aldst[i] = &Asm[i * 4096 + (tid >> 6) * 1024];
  }

  f32x16 acc[2][2];
  #pragma unroll
  for (int mi = 0; mi < 2; ++mi)
    #pragma unroll
    for (int ni = 0; ni < 2; ++ni)
      #pragma unroll
      for (int q = 0; q < 16; ++q) acc[mi][ni][q] = 0.f;

  for (int t = 0; t < NKB; ++t) {
    #pragma unroll
    for (int i = 0; i < 4; ++i)
      async16(abase[i] + ((size_t)t << 8), aldst[i]);

    #pragma unroll
    for (int w = 0; w < 4; ++w) {
      const float* src = wsrc[w] + (size_t)(t * 32) * N;
      float v[8];
      #pragma unroll
      for (int e = 0; e < 8; ++e) v[e] = src[(size_t)e * N];
      us8 o;
      #pragma unroll
      for (int e = 0; e < 8; ++e) {
        unsigned short h = f2bf(v[e]);
        o[e] = wpl[w] ? f2bf(v[e] - bf2f(h)) : h;
      }
      *(us8*)(Wsm + wu[w] * 256 + wss[w] * 16) = o;
    }
    __syncthreads();

    #pragma unroll
    for (int h = 0; h < 2; ++h) {
      const int kb = h * 2 + lhalf;
      bf8 aH[2], aL[2], bH[2], bL[2];
      #pragma unroll
      for (int mi = 0; mi < 2; ++mi) {
        int m = wr * 64 + mi * 32 + ln31;
        int u = m >> 1;
        int sH = (((m & 1) << 3) | kb) ^ (u & 15);
        aH[mi] = *(const bf8*)(Asm + u * 256 + sH * 16);
        aL[mi] = *(const bf8*)(Asm + u * 256 + (sH ^ 4) * 16);
      }
      #pragma unroll
      for (int ni = 0; ni < 2; ++ni) {
        int n = wc * 64 + ni * 32 + ln31;
        int u = n >> 1;
        int sH = (((n & 1) << 3) | kb) ^ (u & 15);
        bH[ni] = *(const bf8*)(Wsm + u * 256 + sH * 16);
        bL[ni] = *(const bf8*)(Wsm + u * 256 + (sH ^ 4) * 16);
      }
      #pragma unroll
      for (int mi = 0; mi < 2; ++mi)
        #pragma unroll
        for (int ni = 0; ni < 2; ++ni) {
          acc[mi][ni] = __builtin_amdgcn_mfma_f32_32x32x16_bf16(aH[mi], bH[ni], acc[mi][ni], 0, 0, 0);
          acc[mi][ni] = __builtin_amdgcn_mfma_f32_32x32x16_bf16(aH[mi], bL[ni], acc[mi][ni], 0, 0, 0);
          acc[mi][ni] = __builtin_amdgcn_mfma_f32_32x32x16_bf16(aL[mi], bH[ni], acc[mi][ni], 0, 0, 0);
        }
    }
    __syncthreads();
  }

  #pragma unroll
  for (int ni = 0; ni < 2; ++ni) {
    int col = N0 + wc * 64 + ni * 32 + ln31;
    float bb = Bv[col];
    #pragma unroll
    for (int mi = 0; mi < 2; ++mi) {
      #pragma unroll
      for (int r = 0; r < 16; ++r) {
        int row = M0 + wr * 64 + mi * 32 + (r & 3) + ((r >> 2) << 3) + (lhalf << 2);
        C[(size_t)row * N + col] = acc[mi][ni][r] + bb;
      }
    }
  }
}

// ---------------------------------------------------------------------------
// MFMA flash attention. 256 threads (4 waves) per block; Q-tile 128 (32 q per
// wave), KV-tile 64. Swapped operands: S^T = mfma(K, Q) so each lane owns one
// q-column -> softmax is in-register + one shfl_xor(32). P packed to bf16 in
// registers, partner-exchanged to form PV B-frags. O^T = mfma(V^T, P^T).
// Epilogue writes packed split-bf16 (out-proj GEMM input).
// ---------------------------------------------------------------------------
__global__ __launch_bounds__(256) void attn_mfma_k(
    const float* __restrict__ Qg, const float* __restrict__ Kg,
    const float* __restrict__ Vg, char* __restrict__ A2)
{
  __shared__ __align__(16) char lds[16384];   // Qt once; then Kt[0..8K) Vt[8K..16K)

  const int bid = blockIdx.x;
  const int swz = (bid & 7) * 64 + (bid >> 3);   // 64 blocks per XCD
  const int qt = swz & 15, h = (swz >> 4) & 15, b = swz >> 8;

  const int tid  = threadIdx.x;
  const int lane = tid & 63;
  const int w    = tid >> 6;
  const int ln31 = lane & 31, lh = lane >> 5;
  const int l7   = ln31 & 7;

  const size_t base = (size_t)b * SEQ * EMBED + (size_t)h * HDIM;
  const int q0 = qt * 128;

  // ---- stage Q (pre-scaled by 1/64) as bf16 [qrow][8 units], unit^(r&7) ----
  {
    const int r0 = tid >> 3, un = tid & 7;
    #pragma unroll
    for (int pass = 0; pass < 4; ++pass) {
      int r = r0 + pass * 32;
      const float* src = Qg + base + (size_t)(q0 + r) * EMBED + un * 8;
      float4 f0 = *(const float4*)(src);
      float4 f1 = *(const float4*)(src + 4);
      float ff[8] = {f0.x, f0.y, f0.z, f0.w, f1.x, f1.y, f1.z, f1.w};
      us8 o;
      #pragma unroll
      for (int e = 0; e < 8; ++e) o[e] = f2bf(ff[e] * 0.015625f);
      *(us8*)(lds + r * 128 + ((un ^ (r & 7)) << 4)) = o;
    }
  }
  __syncthreads();

  // Q B-frags in registers (col q = w*32+ln31, k-dim = d)
  bf8 qf[4];
  {
    const int qr = w * 32 + ln31;
    #pragma unroll
    for (int kd = 0; kd < 4; ++kd)
      qf[kd] = *(const bf8*)(lds + qr * 128 + (((2 * kd + lh) ^ (qr & 7)) << 4));
  }

  f32x16 oacc[2];
  #pragma unroll
  for (int df = 0; df < 2; ++df)
    #pragma unroll
    for (int r = 0; r < 16; ++r) oacc[df][r] = 0.f;
  float m_run = -1e30f, l_run = 0.f;

  for (int t = 0; t < SEQ / 64; ++t) {
    const int k0 = t * 64;
    __syncthreads();   // prev tile consumed (and Qt reads done on t==0)

    // ---- stage K: bf16 [krow][8 units], unit^(r&7) ----
    {
      const int r0 = tid >> 3, un = tid & 7;
      #pragma unroll
      for (int pass = 0; pass < 2; ++pass) {
        int r = r0 + pass * 32;
        const float* src = Kg + base + (size_t)(k0 + r) * EMBED + un * 8;
        float4 f0 = *(const float4*)(src);
        float4 f1 = *(const float4*)(src + 4);
        float ff[8] = {f0.x, f0.y, f0.z, f0.w, f1.x, f1.y, f1.z, f1.w};
        us8 o;
        #pragma unroll
        for (int e = 0; e < 8; ++e) o[e] = f2bf(ff[e]);
        *(us8*)(lds + r * 128 + ((un ^ (r & 7)) << 4)) = o;
      }
    }
    // ---- stage V^T: u32 pairs (k,k+1) at [d][kpair], 16B-unit swizzled ----
    {
      const int kp = tid & 31, d8 = (tid >> 5) * 8;
      const float* s0 = Vg + base + (size_t)(k0 + 2 * kp) * EMBED + d8;
      const float* s1 = s0 + EMBED;
      float4 a0 = *(const float4*)(s0);
      float4 a1 = *(const float4*)(s0 + 4);
      float4 c0 = *(const float4*)(s1);
      float4 c1 = *(const float4*)(s1 + 4);
      float r0f[8] = {a0.x, a0.y, a0.z, a0.w, a1.x, a1.y, a1.z, a1.w};
      float r1f[8] = {c0.x, c0.y, c0.z, c0.w, c1.x, c1.y, c1.z, c1.w};
      #pragma unroll
      for (int j = 0; j < 8; ++j) {
        unsigned pr = (unsigned)f2bf(r0f[j]) | ((unsigned)f2bf(r1f[j]) << 16);
        int d = d8 + j;
        *(unsigned*)(lds + 8192 + d * 128 + ((((kp >> 2) ^ (d & 7)) << 4)) + ((kp & 3) << 2)) = pr;
      }
    }
    __syncthreads();

    // ---- S^T = K * Q^T (rows k, cols q) ----
    f32x16 sacc[2];
    #pragma unroll
    for (int kf = 0; kf < 2; ++kf)
      #pragma unroll
      for (int r = 0; r < 16; ++r) sacc[kf][r] = 0.f;
    #pragma unroll
    for (int kf = 0; kf < 2; ++kf)
      #pragma unroll
      for (int kd = 0; kd < 4; ++kd) {
        bf8 ka = *(const bf8*)(lds + (32 * kf + ln31) * 128 + (((2 * kd + lh) ^ l7) << 4));
        sacc[kf] = __builtin_amdgcn_mfma_f32_32x32x16_bf16(ka, qf[kd], sacc[kf], 0, 0, 0);
      }

    // ---- online softmax (lane owns col q; 32 of 64 k here, rest in partner) ----
    float mx = -1e30f;
    #pragma unroll
    for (int kf = 0; kf < 2; ++kf)
      #pragma unroll
      for (int r = 0; r < 16; ++r) mx = fmaxf(mx, sacc[kf][r]);
    mx = fmaxf(mx, __shfl_xor(mx, 32));
    float mnew = fmaxf(m_run, mx);
    float corr = __expf(m_run - mnew);
    float psum = 0.f;
    #pragma unroll
    for (int kf = 0; kf < 2; ++kf)
      #pragma unroll
      for (int r = 0; r < 16; ++r) {
        float p = __expf(sacc[kf][r] - mnew);
        sacc[kf][r] = p; psum += p;
      }
    psum += __shfl_xor(psum, 32);
    m_run = mnew;
    l_run = l_run * corr + psum;
    #pragma unroll
    for (int df = 0; df < 2; ++df)
      #pragma unroll
      for (int r = 0; r < 16; ++r) oacc[df][r] *= corr;

    // ---- pack P to bf16 pairs; exchange with partner lane ----
    unsigned pk[2][8], sw[2][8];
    #pragma unroll
    for (int kf = 0; kf < 2; ++kf)
      #pragma unroll
      for (int g = 0; g < 4; ++g)
        #pragma unroll
        for (int j = 0; j < 2; ++j)
          pk[kf][2 * g + j] = (unsigned)f2bf(sacc[kf][4 * g + 2 * j]) |
                              ((unsigned)f2bf(sacc[kf][4 * g + 2 * j + 1]) << 16);
    #pragma unroll
    for (int kf = 0; kf < 2; ++kf)
      #pragma unroll
      for (int j = 0; j < 8; ++j)
        sw[kf][j] = (unsigned)__shfl_xor((int)pk[kf][j], 32);

    // ---- O^T += V^T * P^T ----
    #pragma unroll
    for (int kb = 0; kb < 4; ++kb) {
      const int kf = kb >> 1, b4 = (kb & 1) * 4;
      union { unsigned u[4]; bf8 v; } pf;
      pf.u[0] = lh ? sw[kf][b4 + 2] : pk[kf][b4 + 0];
      pf.u[1] = lh ? sw[kf][b4 + 3] : pk[kf][b4 + 1];
      pf.u[2] = lh ? pk[kf][b4 + 2] : sw[kf][b4 + 0];
      pf.u[3] = lh ? pk[kf][b4 + 3] : sw[kf][b4 + 1];
      #pragma unroll
      for (int df = 0; df < 2; ++df) {
        bf8 va = *(const bf8*)(lds + 8192 + (32 * df + ln31) * 128 + (((2 * kb + lh) ^ l7) << 4));
        oacc[df] = __builtin_amdgcn_mfma_f32_32x32x16_bf16(va, pf.v, oacc[df], 0, 0, 0);
      }
    }
  }

  // ---- epilogue: normalize, partner-exchange, write packed split-bf16 ----
  const float inv = 1.0f / l_run;
  float own[8][4], swp[8][4];
  #pragma unroll
  for (int df = 0; df < 2; ++df)
    #pragma unroll
    for (int r = 0; r < 16; ++r)
      own[df * 4 + (r >> 2)][r & 3] = oacc[df][r] * inv;
  #pragma unroll
  for (int g = 0; g < 8; ++g)
    #pragma unroll
    for (int j = 0; j < 4; ++j)
      swp[g][j] = __shfl_xor(own[g][j], 32);

  const int row = b * SEQ + q0 + w * 32 + ln31;
  const int u = row >> 1, par = row & 1;
  #pragma unroll
  for (int g = 0; g < 8; ++g) {
    float f[8];
    #pragma unroll
    for (int e = 0; e < 8; ++e) {
      int j = e & 3;
      f[e] = (e < 4) ? (lh ? swp[g][j] : own[g][j])
                     : (lh ? own[g][j] : swp[g][j]);
    }
    us8 hi, lo;
    #pragma unroll
    for (int e = 0; e < 8; ++e) {
      unsigned short h8 = f2bf(f[e]);
      hi[e] = h8;
      lo[e] = f2bf(f[e] - bf2f(h8));
    }
    int t_blk = 2 * h + (g >> 2), kb8 = g & 3;
    size_t ub = ((size_t)(u * NKB + t_blk)) << 8;
    int sH = ((par << 3) | kb8) ^ (u & 15);
    *(us8*)(A2 + ub + (sH << 4)) = hi;
    *(us8*)(A2 + ub + ((sH ^ 4) << 4)) = lo;
  }
}

// ---------------------------------------------------------------------------
extern "C" void kernel_launch(void* const* d_in, const int* in_sizes, int n_in,
                              void* d_out, int out_size, void* d_ws, size_t ws_size,
                              hipStream_t stream)
{
  const float* x  = (const float*)d_in[0];
  const float* Wq = (const float*)d_in[1];
  const float* bq = (const float*)d_in[2];
  const float* Wk = (const float*)d_in[3];
  const float* bk = (const float*)d_in[4];
  const float* Wv = (const float*)d_in[5];
  const float* bv = (const float*)d_in[6];
  const float* Wo = (const float*)d_in[7];
  const float* bo = (const float*)d_in[8];
  float* out = (float*)d_out;

  char* wsb = (char*)d_ws;
  float* Qb = (float*)(wsb);
  float* Kb = (float*)(wsb + ((size_t)16 << 20));
  float* Vb = (float*)(wsb + ((size_t)32 << 20));
  char*  R  = wsb + ((size_t)48 << 20);   // Xpack, later A2pack (16MB)

  const int nslots = (MROWS / 2) * NKB * 16;
  pack_rows_k<<<dim3(nslots / 256), dim3(256), 0, stream>>>(x, R, nslots);

  gemm_mfma_k<<<dim3(768), dim3(256), 0, stream>>>(
      R, Wq, Wk, Wv, bq, bk, bv, Qb, Kb, Vb, 3);

  attn_mfma_k<<<dim3(512), dim3(256), 0, stream>>>(Qb, Kb, Vb, R);

  gemm_mfma_k<<<dim3(256), dim3(256), 0, stream>>>(
      R, Wo, Wo, Wo, bo, bo, bo, out, out, out, 1);
}

// Round 5
// 232.916 us; speedup vs baseline: 8.6046x; 1.4541x over previous
//
#include <hip/hip_runtime.h>

constexpr int EMBED = 1024;
constexpr int NHEAD = 16;
constexpr int HDIM  = 64;
constexpr int BATCH = 2;
constexpr int SEQ   = 2048;
constexpr int MROWS = BATCH * SEQ;   // 4096
constexpr int NKB   = EMBED / 32;    // 32 k-blocks of 32

typedef __attribute__((ext_vector_type(8)))  short          bf8;   // 8 bf16 (4 VGPR)
typedef __attribute__((ext_vector_type(8)))  unsigned short us8;
typedef __attribute__((ext_vector_type(16))) float          f32x16;

__device__ __forceinline__ unsigned short f2bf(float f) {  // RNE fp32->bf16
  unsigned u = __float_as_uint(f);
  u += 0x7fffu + ((u >> 16) & 1u);
  return (unsigned short)(u >> 16);
}
__device__ __forceinline__ float bf2f(unsigned short h) {
  return __uint_as_float((unsigned)h << 16);
}
__device__ __forceinline__ void async16(const void* g, void* l) {
  __builtin_amdgcn_global_load_lds(
      (const __attribute__((address_space(1))) unsigned int*)g,
      (__attribute__((address_space(3))) unsigned int*)l, 16, 0, 0);
}

// ---------------------------------------------------------------------------
// Pack row-major fp32 [R][1024] into split-bf16 256B-unit layout:
// unit u = row-pair; slot s holds c = s ^ (u&15) -> {par=c>>3, pl=(c>>2)&1,
// kb8=c&3}: 8 bf16 of plane(hi/lo) of row 2u+par, k = t*32+kb8*8..+8.
// ---------------------------------------------------------------------------
__global__ __launch_bounds__(256) void pack_rows_k(
    const float* __restrict__ in, char* __restrict__ outp, int nslots)
{
  int sid = blockIdx.x * 256 + threadIdx.x;
  if (sid >= nslots) return;
  int s = sid & 15;
  int t = (sid >> 4) & (NKB - 1);
  int u = sid >> 9;
  int c = s ^ (u & 15);
  int par = c >> 3, pl = (c >> 2) & 1, kb8 = c & 3;
  const float* src = in + (size_t)(2 * u + par) * EMBED + t * 32 + kb8 * 8;
  us8 o;
  #pragma unroll
  for (int e = 0; e < 8; ++e) {
    float f = src[e];
    unsigned short h = f2bf(f);
    o[e] = pl ? f2bf(f - bf2f(h)) : h;
  }
  *(us8*)(outp + ((size_t)sid << 4)) = o;
}

// ---------------------------------------------------------------------------
// Pack W (fp32 [K][N]) TRANSPOSED into the same unit layout keyed by column:
// unit u = column-pair. Strided reads; L2 absorbs the per-line re-reads.
// blockIdx.y selects among 4 weight matrices (out at y*4MB).
// ---------------------------------------------------------------------------
__global__ __launch_bounds__(256) void pack_wt_k(
    const float* __restrict__ W0, const float* __restrict__ W1,
    const float* __restrict__ W2, const float* __restrict__ W3,
    char* __restrict__ outp)
{
  const int y = blockIdx.y;
  const float* W = (y == 0) ? W0 : (y == 1) ? W1 : (y == 2) ? W2 : W3;
  char* op = outp + ((size_t)y << 22);
  int sid = blockIdx.x * 256 + threadIdx.x;   // 0..262143
  int s = sid & 15;
  int t = (sid >> 4) & (NKB - 1);
  int u = sid >> 9;                            // 0..511 (column-pair)
  int c = s ^ (u & 15);
  int par = c >> 3, pl = (c >> 2) & 1, kb8 = c & 3;
  const float* src = W + (size_t)(t * 32 + kb8 * 8) * EMBED + (2 * u + par);
  us8 o;
  #pragma unroll
  for (int e = 0; e < 8; ++e) {
    float f = src[(size_t)e * EMBED];
    unsigned short h = f2bf(f);
    o[e] = pl ? f2bf(f - bf2f(h)) : h;
  }
  *(us8*)(op + ((size_t)sid << 4)) = o;
}

// ---------------------------------------------------------------------------
// Split-bf16 MFMA GEMM, both operands pre-packed. 128x128 tile, BK=32,
// 4 waves (2x2), per-wave 2x2 frags of 32x32x16, 3-term split.
// K-loop: 8 global_load_lds + 16 ds_read_b128 + 24 MFMA, no VALU staging.
// nz==3: bf16 outputs (z==0 scaled by 1/64);  nz==1: fp32 output + bias.
// ---------------------------------------------------------------------------
__global__ __launch_bounds__(256) void gemm_mfma_k(
    const char* __restrict__ Apack, const char* __restrict__ Wpack,
    const float* __restrict__ B0, const float* __restrict__ B1, const float* __restrict__ B2,
    float* __restrict__ Cf,
    unsigned short* __restrict__ Cb0, unsigned short* __restrict__ Cb1,
    unsigned short* __restrict__ Cb2,
    int nz)
{
  constexpr int N = EMBED;
  __shared__ __align__(16) char Asm[16384];
  __shared__ __align__(16) char Wsm[16384];

  const int tid  = threadIdx.x;
  const int lane = tid & 63;
  const int wid  = tid >> 6;
  const int wr   = wid >> 1, wc = wid & 1;
  const int ln31 = lane & 31, lhalf = lane >> 5;

  const int nwg = gridDim.x;
  const int per = nwg >> 3;
  const int bid = blockIdx.x;
  const int swz = (bid & 7) * per + (bid >> 3);
  const int zc  = nz << 3;
  const int rp  = swz / zc;
  const int sub = swz - rp * zc;
  const int z   = sub >> 3, cb = sub & 7;

  const char*  Wz = Wpack + ((size_t)z << 22);
  const float* Bv = (z == 0) ? B0 : (z == 1) ? B1 : B2;

  const int M0 = rp * 128, N0 = cb * 128;
  const int U0 = M0 >> 1, V0 = N0 >> 1;

  const char* abase[4]; char* aldst[4];
  const char* wbase[4]; char* wldst[4];
  #pragma unroll
  for (int i = 0; i < 4; ++i) {
    int ul = i * 16 + (tid >> 4);
    int so = (tid & 15) << 4;
    abase[i] = Apack + (((size_t)(U0 + ul) * NKB) << 8) + so;
    wbase[i] = Wz    + (((size_t)(V0 + ul) * NKB) << 8) + so;
    aldst[i] = &Asm[i * 4096 + (tid >> 6) * 1024];
    wldst[i] = &Wsm[i * 4096 + (tid >> 6) * 1024];
  }

  f32x16 acc[2][2];
  #pragma unroll
  for (int mi = 0; mi < 2; ++mi)
    #pragma unroll
    for (int ni = 0; ni < 2; ++ni)
      #pragma unroll
      for (int q = 0; q < 16; ++q) acc[mi][ni][q] = 0.f;

  for (int t = 0; t < NKB; ++t) {
    #pragma unroll
    for (int i = 0; i < 4; ++i) {
      async16(abase[i] + ((size_t)t << 8), aldst[i]);
      async16(wbase[i] + ((size_t)t << 8), wldst[i]);
    }
    __syncthreads();   // drains vmcnt + barrier

    #pragma unroll
    for (int h = 0; h < 2; ++h) {
      const int kb = h * 2 + lhalf;
      bf8 aH[2], aL[2], bH[2], bL[2];
      #pragma unroll
      for (int mi = 0; mi < 2; ++mi) {
        int m = wr * 64 + mi * 32 + ln31;
        int u = m >> 1;
        int sH = (((m & 1) << 3) | kb) ^ (u & 15);
        aH[mi] = *(const bf8*)(Asm + u * 256 + sH * 16);
        aL[mi] = *(const bf8*)(Asm + u * 256 + (sH ^ 4) * 16);
      }
      #pragma unroll
      for (int ni = 0; ni < 2; ++ni) {
        int n = wc * 64 + ni * 32 + ln31;
        int u = n >> 1;
        int sH = (((n & 1) << 3) | kb) ^ (u & 15);
        bH[ni] = *(const bf8*)(Wsm + u * 256 + sH * 16);
        bL[ni] = *(const bf8*)(Wsm + u * 256 + (sH ^ 4) * 16);
      }
      #pragma unroll
      for (int mi = 0; mi < 2; ++mi)
        #pragma unroll
        for (int ni = 0; ni < 2; ++ni) {
          acc[mi][ni] = __builtin_amdgcn_mfma_f32_32x32x16_bf16(aH[mi], bH[ni], acc[mi][ni], 0, 0, 0);
          acc[mi][ni] = __builtin_amdgcn_mfma_f32_32x32x16_bf16(aH[mi], bL[ni], acc[mi][ni], 0, 0, 0);
          acc[mi][ni] = __builtin_amdgcn_mfma_f32_32x32x16_bf16(aL[mi], bH[ni], acc[mi][ni], 0, 0, 0);
        }
    }
    __syncthreads();
  }

  if (nz == 1) {
    #pragma unroll
    for (int ni = 0; ni < 2; ++ni) {
      int col = N0 + wc * 64 + ni * 32 + ln31;
      float bb = Bv[col];
      #pragma unroll
      for (int mi = 0; mi < 2; ++mi)
        #pragma unroll
        for (int r = 0; r < 16; ++r) {
          int row = M0 + wr * 64 + mi * 32 + (r & 3) + ((r >> 2) << 3) + (lhalf << 2);
          Cf[(size_t)row * N + col] = acc[mi][ni][r] + bb;
        }
    }
  } else {
    unsigned short* Cb = (z == 0) ? Cb0 : (z == 1) ? Cb1 : Cb2;
    const float sc = (z == 0) ? 0.015625f : 1.0f;   // fold scores/64 into Q
    #pragma unroll
    for (int ni = 0; ni < 2; ++ni) {
      int col = N0 + wc * 64 + ni * 32 + ln31;
      float bb = Bv[col];
      #pragma unroll
      for (int mi = 0; mi < 2; ++mi)
        #pragma unroll
        for (int r = 0; r < 16; ++r) {
          int row = M0 + wr * 64 + mi * 32 + (r & 3) + ((r >> 2) << 3) + (lhalf << 2);
          Cb[(size_t)row * N + col] = f2bf((acc[mi][ni][r] + bb) * sc);
        }
    }
  }
}

// ---------------------------------------------------------------------------
// MFMA flash attention on bf16 Q/K/V. 256 threads; Q-tile 128, KV-tile 64.
// S^T = mfma(K, Q): lane owns one q-column -> in-register softmax + one
// shfl_xor(32). P bf16-packed in regs, partner-exchanged -> PV B-frags.
// O^T = mfma(V^T, P^T). K staged via pre-swizzled-source global_load_lds;
// V^T via u16-pair interleave; Q frags straight from global (pre-scaled).
// ---------------------------------------------------------------------------
__global__ __launch_bounds__(256) void attn_mfma_k(
    const unsigned short* __restrict__ Qb, const unsigned short* __restrict__ Kb,
    const unsigned short* __restrict__ Vb, char* __restrict__ A2)
{
  __shared__ __align__(16) char lds[16384];   // K [0,8K) | V^T [8K,16K)

  const int bid = blockIdx.x;
  const int swz = (bid & 7) * 64 + (bid >> 3);
  const int qt = swz & 15, h = (swz >> 4) & 15, b = swz >> 8;

  const int tid  = threadIdx.x;
  const int lane = tid & 63;
  const int w    = tid >> 6;
  const int ln31 = lane & 31, lh = lane >> 5;
  const int l7   = ln31 & 7;

  const int q0 = qt * 128;

  // Q fragments direct from global (already scaled by 1/64 in GEMM epilogue)
  bf8 qf[4];
  {
    const size_t qoff = (size_t)(b * SEQ + q0 + w * 32 + ln31) * EMBED + h * HDIM;
    #pragma unroll
    for (int kd = 0; kd < 4; ++kd)
      qf[kd] = *(const bf8*)(Qb + qoff + (2 * kd + lh) * 8);
  }

  f32x16 oacc[2];
  #pragma unroll
  for (int df = 0; df < 2; ++df)
    #pragma unroll
    for (int r = 0; r < 16; ++r) oacc[df][r] = 0.f;
  float m_run = -1e30f, l_run = 0.f;

  for (int t = 0; t < SEQ / 64; ++t) {
    const int k0 = t * 64;
    __syncthreads();   // prev tile consumed

    // K stage: image slot (r, si) holds source unit si^(r&7)  (m173 pattern)
    #pragma unroll
    for (int i = 0; i < 2; ++i) {
      int slot = tid + (i << 8);
      int r = slot >> 3, s7 = slot & 7;
      int un = s7 ^ (r & 7);
      async16(Kb + (size_t)(b * SEQ + k0 + r) * EMBED + h * HDIM + un * 8,
              lds + i * 4096 + (tid >> 6) * 1024);
    }
    // V^T stage: u32 = (bf16 row2kp, bf16 row2kp+1) at [d][kpair], swizzled
    {
      int kp = tid & 31, d8 = (tid >> 5) << 3;
      const unsigned short* s0 = Vb + (size_t)(b * SEQ + k0 + 2 * kp) * EMBED + h * HDIM + d8;
      us8 v0 = *(const us8*)(s0);
      us8 v1 = *(const us8*)(s0 + EMBED);
      #pragma unroll
      for (int j = 0; j < 8; ++j) {
        unsigned pr = (unsigned)v0[j] | ((unsigned)v1[j] << 16);
        int d = d8 + j;
        *(unsigned*)(lds + 8192 + d * 128 + (((kp >> 2) ^ (d & 7)) << 4) + ((kp & 3) << 2)) = pr;
      }
    }
    __syncthreads();

    // S^T = K * Q^T
    f32x16 sacc[2];
    #pragma unroll
    for (int kf = 0; kf < 2; ++kf)
      #pragma unroll
      for (int r = 0; r < 16; ++r) sacc[kf][r] = 0.f;
    #pragma unroll
    for (int kf = 0; kf < 2; ++kf)
      #pragma unroll
      for (int kd = 0; kd < 4; ++kd) {
        bf8 ka = *(const bf8*)(lds + (32 * kf + ln31) * 128 + (((2 * kd + lh) ^ l7) << 4));
        sacc[kf] = __builtin_amdgcn_mfma_f32_32x32x16_bf16(ka, qf[kd], sacc[kf], 0, 0, 0);
      }

    // online softmax (lane owns q-col; partner lane has other 32 k-rows)
    float mx = -1e30f;
    #pragma unroll
    for (int kf = 0; kf < 2; ++kf)
      #pragma unroll
      for (int r = 0; r < 16; ++r) mx = fmaxf(mx, sacc[kf][r]);
    mx = fmaxf(mx, __shfl_xor(mx, 32));
    float mnew = fmaxf(m_run, mx);
    float corr = __expf(m_run - mnew);
    float psum = 0.f;
    #pragma unroll
    for (int kf = 0; kf < 2; ++kf)
      #pragma unroll
      for (int r = 0; r < 16; ++r) {
        float p = __expf(sacc[kf][r] - mnew);
        sacc[kf][r] = p; psum += p;
      }
    psum += __shfl_xor(psum, 32);
    m_run = mnew;
    l_run = l_run * corr + psum;
    #pragma unroll
    for (int df = 0; df < 2; ++df)
      #pragma unroll
      for (int r = 0; r < 16; ++r) oacc[df][r] *= corr;

    // pack P to bf16 pairs; partner exchange
    unsigned pk[2][8], sw[2][8];
    #pragma unroll
    for (int kf = 0; kf < 2; ++kf)
      #pragma unroll
      for (int g = 0; g < 4; ++g)
        #pragma unroll
        for (int j = 0; j < 2; ++j)
          pk[kf][2 * g + j] = (unsigned)f2bf(sacc[kf][4 * g + 2 * j]) |
                              ((unsigned)f2bf(sacc[kf][4 * g + 2 * j + 1]) << 16);
    #pragma unroll
    for (int kf = 0; kf < 2; ++kf)
      #pragma unroll
      for (int j = 0; j < 8; ++j)
        sw[kf][j] = (unsigned)__shfl_xor((int)pk[kf][j], 32);

    // O^T += V^T * P^T
    #pragma unroll
    for (int kb = 0; kb < 4; ++kb) {
      const int kf = kb >> 1, b4 = (kb & 1) * 4;
      union { unsigned u[4]; bf8 v; } pf;
      pf.u[0] = lh ? sw[kf][b4 + 2] : pk[kf][b4 + 0];
      pf.u[1] = lh ? sw[kf][b4 + 3] : pk[kf][b4 + 1];
      pf.u[2] = lh ? pk[kf][b4 + 2] : sw[kf][b4 + 0];
      pf.u[3] = lh ? pk[kf][b4 + 3] : sw[kf][b4 + 1];
      #pragma unroll
      for (int df = 0; df < 2; ++df) {
        bf8 va = *(const bf8*)(lds + 8192 + (32 * df + ln31) * 128 + (((2 * kb + lh) ^ l7) << 4));
        oacc[df] = __builtin_amdgcn_mfma_f32_32x32x16_bf16(va, pf.v, oacc[df], 0, 0, 0);
      }
    }
  }

  // epilogue: normalize, partner-exchange, write packed split-bf16
  const float inv = 1.0f / l_run;
  float own[8][4], swp[8][4];
  #pragma unroll
  for (int df = 0; df < 2; ++df)
    #pragma unroll
    for (int r = 0; r < 16; ++r)
      own[df * 4 + (r >> 2)][r & 3] = oacc[df][r] * inv;
  #pragma unroll
  for (int g = 0; g < 8; ++g)
    #pragma unroll
    for (int j = 0; j < 4; ++j)
      swp[g][j] = __shfl_xor(own[g][j], 32);

  const int row = b * SEQ + q0 + w * 32 + ln31;
  const int u = row >> 1, par = row & 1;
  #pragma unroll
  for (int g = 0; g < 8; ++g) {
    float f[8];
    #pragma unroll
    for (int e = 0; e < 8; ++e) {
      int j = e & 3;
      f[e] = (e < 4) ? (lh ? swp[g][j] : own[g][j])
                     : (lh ? own[g][j] : swp[g][j]);
    }
    us8 hi, lo;
    #pragma unroll
    for (int e = 0; e < 8; ++e) {
      unsigned short h8 = f2bf(f[e]);
      hi[e] = h8;
      lo[e] = f2bf(f[e] - bf2f(h8));
    }
    int t_blk = 2 * h + (g >> 2), kb8 = g & 3;
    size_t ub = ((size_t)(u * NKB + t_blk)) << 8;
    int sH = ((par << 3) | kb8) ^ (u & 15);
    *(us8*)(A2 + ub + (sH << 4)) = hi;
    *(us8*)(A2 + ub + ((sH ^ 4) << 4)) = lo;
  }
}

// ---------------------------------------------------------------------------
extern "C" void kernel_launch(void* const* d_in, const int* in_sizes, int n_in,
                              void* d_out, int out_size, void* d_ws, size_t ws_size,
                              hipStream_t stream)
{
  const float* x  = (const float*)d_in[0];
  const float* Wq = (const float*)d_in[1];
  const float* bq = (const float*)d_in[2];
  const float* Wk = (const float*)d_in[3];
  const float* bk = (const float*)d_in[4];
  const float* Wv = (const float*)d_in[5];
  const float* bv = (const float*)d_in[6];
  const float* Wo = (const float*)d_in[7];
  const float* bo = (const float*)d_in[8];
  float* out = (float*)d_out;

  char* wsb = (char*)d_ws;
  char*           R   = wsb;                                    // 16MB: Xpack, then A2pack
  unsigned short* Qbf = (unsigned short*)(wsb + ((size_t)16 << 20));  // 8MB
  unsigned short* Kbf = (unsigned short*)(wsb + ((size_t)24 << 20));  // 8MB
  unsigned short* Vbf = (unsigned short*)(wsb + ((size_t)32 << 20));  // 8MB
  char*           Wpk = wsb + ((size_t)40 << 20);               // 16MB (4 x 4MB)

  const int nslots = (MROWS / 2) * NKB * 16;   // 1,048,576
  pack_rows_k<<<dim3(nslots / 256), dim3(256), 0, stream>>>(x, R, nslots);
  pack_wt_k<<<dim3(1024, 4), dim3(256), 0, stream>>>(Wq, Wk, Wv, Wo, Wpk);

  gemm_mfma_k<<<dim3(768), dim3(256), 0, stream>>>(
      R, Wpk, bq, bk, bv, nullptr, Qbf, Kbf, Vbf, 3);

  attn_mfma_k<<<dim3(512), dim3(256), 0, stream>>>(Qbf, Kbf, Vbf, R);

  gemm_mfma_k<<<dim3(256), dim3(256), 0, stream>>>(
      R, Wpk + ((size_t)3 << 22), bo, bo, bo, out, nullptr, nullptr, nullptr, 1);
}

// Round 6
// 176.246 us; speedup vs baseline: 11.3714x; 1.3215x over previous
//
#include <hip/hip_runtime.h>

constexpr int EMBED = 1024;
constexpr int NHEAD = 16;
constexpr int HDIM  = 64;
constexpr int BATCH = 2;
constexpr int SEQ   = 2048;
constexpr int MROWS = BATCH * SEQ;   // 4096
constexpr int NKB   = EMBED / 32;    // 32 k-blocks of 32
constexpr int NT    = SEQ / 64;      // 32 KV tiles

typedef __attribute__((ext_vector_type(8)))  short          bf8;
typedef __attribute__((ext_vector_type(8)))  unsigned short us8;
typedef __attribute__((ext_vector_type(16))) float          f32x16;

__device__ __forceinline__ unsigned short f2bf(float f) {  // RNE fp32->bf16
  unsigned u = __float_as_uint(f);
  u += 0x7fffu + ((u >> 16) & 1u);
  return (unsigned short)(u >> 16);
}
__device__ __forceinline__ float bf2f(unsigned short h) {
  return __uint_as_float((unsigned)h << 16);
}
__device__ __forceinline__ void async16(const void* g, void* l) {
  __builtin_amdgcn_global_load_lds(
      (const __attribute__((address_space(1))) unsigned int*)g,
      (__attribute__((address_space(3))) unsigned int*)l, 16, 0, 0);
}

// ---------------------------------------------------------------------------
// bf16 pack of x: unit u = row-pair, 128B per (u,t): 8 slots of 16B.
// slot s holds c = s^(u&7): par=c>>2 (row 2u+par), kq=c&3 (k=t*32+kq*8).
// addr = (u*32 + t)*128 + s*16.  Layout == LDS image (linear async16).
// ---------------------------------------------------------------------------
__global__ __launch_bounds__(256) void pack_x_bf16_k(
    const float* __restrict__ in, char* __restrict__ outp)
{
  int sid = blockIdx.x * 256 + threadIdx.x;   // 0..524287
  int s = sid & 7, t = (sid >> 3) & 31, u = sid >> 8;
  int c = s ^ (u & 7);
  int par = c >> 2, kq = c & 3;
  const float* src = in + (size_t)(2 * u + par) * EMBED + t * 32 + kq * 8;
  us8 o;
  #pragma unroll
  for (int e = 0; e < 8; ++e) o[e] = f2bf(src[e]);
  *(us8*)(outp + ((size_t)sid << 4)) = o;
}

// bf16 pack of W^T (keyed by column-pair), 3 matrices (y selects), 2MB each.
__global__ __launch_bounds__(256) void pack_w_bf16_k(
    const float* __restrict__ W0, const float* __restrict__ W1,
    const float* __restrict__ W2, char* __restrict__ outp)
{
  const int y = blockIdx.y;
  const float* W = (y == 0) ? W0 : (y == 1) ? W1 : W2;
  char* op = outp + ((size_t)y << 21);
  int sid = blockIdx.x * 256 + threadIdx.x;   // 0..131071
  int s = sid & 7, t = (sid >> 3) & 31, u = sid >> 8;   // u: col-pair 0..511
  int c = s ^ (u & 7);
  int par = c >> 2, kq = c & 3;
  const float* src = W + (size_t)(t * 32 + kq * 8) * EMBED + (2 * u + par);
  us8 o;
  #pragma unroll
  for (int e = 0; e < 8; ++e) o[e] = f2bf(src[(size_t)e * EMBED]);
  *(us8*)(op + ((size_t)sid << 4)) = o;
}

// split-bf16 pack of Wo^T (256B units, 16 slots: par/plane/kb8), 4MB.
__global__ __launch_bounds__(256) void pack_wo_split_k(
    const float* __restrict__ W, char* __restrict__ outp)
{
  int sid = blockIdx.x * 256 + threadIdx.x;   // 0..262143
  int s = sid & 15, t = (sid >> 4) & 31, u = sid >> 9;   // u: col-pair 0..511
  int c = s ^ (u & 15);
  int par = c >> 3, pl = (c >> 2) & 1, kb8 = c & 3;
  const float* src = W + (size_t)(t * 32 + kb8 * 8) * EMBED + (2 * u + par);
  us8 o;
  #pragma unroll
  for (int e = 0; e < 8; ++e) {
    float f = src[(size_t)e * EMBED];
    unsigned short h = f2bf(f);
    o[e] = pl ? f2bf(f - bf2f(h)) : h;
  }
  *(us8*)(outp + ((size_t)sid << 4)) = o;
}

// ---------------------------------------------------------------------------
// QKV GEMM, plain bf16, double-buffered 2-phase. 128x128 tile, BK=32,
// 4 waves (2x2), 2x2 frags of 32x32x16, 8 MFMA + 8 ds_read_b128 / K-step.
// Outputs bf16 (z==0 pre-scaled by 1/64 for the attention scores).
// ---------------------------------------------------------------------------
__global__ __launch_bounds__(256) void gemm_qkv_bf16_k(
    const char* __restrict__ Apk, const char* __restrict__ Wpk,
    const float* __restrict__ B0, const float* __restrict__ B1, const float* __restrict__ B2,
    unsigned short* __restrict__ Cb0, unsigned short* __restrict__ Cb1,
    unsigned short* __restrict__ Cb2)
{
  __shared__ __align__(16) char Asm[16384];   // 2 x 8KB
  __shared__ __align__(16) char Wsm[16384];

  const int tid  = threadIdx.x;
  const int lane = tid & 63;
  const int wid  = tid >> 6;
  const int wr   = wid >> 1, wc = wid & 1;
  const int ln31 = lane & 31, lhalf = lane >> 5;

  const int bid = blockIdx.x;                 // 768 blocks
  const int swz = (bid & 7) * 96 + (bid >> 3);
  const int rp  = swz / 24;
  const int sub = swz - rp * 24;
  const int z   = sub >> 3, cb = sub & 7;

  const char*  Wz = Wpk + ((size_t)z << 21);
  const float* Bv = (z == 0) ? B0 : (z == 1) ? B1 : B2;

  const int M0 = rp * 128, N0 = cb * 128;
  const int U0 = M0 >> 1, V0 = N0 >> 1;

  const char* ab[2]; const char* wb[2]; int ldoff[2];
  #pragma unroll
  for (int i = 0; i < 2; ++i) {
    int idx = i * 256 + tid;
    int ul = idx >> 3, sl = idx & 7;
    ab[i] = Apk + ((size_t)(U0 + ul) << 12) + (sl << 4);
    wb[i] = Wz  + ((size_t)(V0 + ul) << 12) + (sl << 4);
    ldoff[i] = i * 4096 + (tid >> 6) * 1024;
  }

  f32x16 acc[2][2];
  #pragma unroll
  for (int mi = 0; mi < 2; ++mi)
    #pragma unroll
    for (int ni = 0; ni < 2; ++ni)
      #pragma unroll
      for (int q = 0; q < 16; ++q) acc[mi][ni][q] = 0.f;

  // prologue stage t=0 -> buf0
  #pragma unroll
  for (int i = 0; i < 2; ++i) {
    async16(ab[i], &Asm[ldoff[i]]);
    async16(wb[i], &Wsm[ldoff[i]]);
  }
  __syncthreads();

  for (int t = 0; t < NKB; ++t) {
    const int c = t & 1;
    if (t + 1 < NKB) {
      #pragma unroll
      for (int i = 0; i < 2; ++i) {
        async16(ab[i] + ((t + 1) << 7), &Asm[(c ^ 1) * 8192 + ldoff[i]]);
        async16(wb[i] + ((t + 1) << 7), &Wsm[(c ^ 1) * 8192 + ldoff[i]]);
      }
    }
    const char* Ab = Asm + c * 8192;
    const char* Wb = Wsm + c * 8192;
    #pragma unroll
    for (int kb = 0; kb < 2; ++kb) {
      const int kq = (kb << 1) | lhalf;
      bf8 a[2], b[2];
      #pragma unroll
      for (int mi = 0; mi < 2; ++mi) {
        int m = wr * 64 + mi * 32 + ln31;
        int u = m >> 1;
        int s = (((m & 1) << 2) | kq) ^ (u & 7);
        a[mi] = *(const bf8*)(Ab + u * 128 + s * 16);
      }
      #pragma unroll
      for (int ni = 0; ni < 2; ++ni) {
        int n = wc * 64 + ni * 32 + ln31;
        int u = n >> 1;
        int s = (((n & 1) << 2) | kq) ^ (u & 7);
        b[ni] = *(const bf8*)(Wb + u * 128 + s * 16);
      }
      #pragma unroll
      for (int mi = 0; mi < 2; ++mi)
        #pragma unroll
        for (int ni = 0; ni < 2; ++ni)
          acc[mi][ni] = __builtin_amdgcn_mfma_f32_32x32x16_bf16(a[mi], b[ni], acc[mi][ni], 0, 0, 0);
    }
    __syncthreads();
  }

  unsigned short* Cb = (z == 0) ? Cb0 : (z == 1) ? Cb1 : Cb2;
  const float sc = (z == 0) ? 0.015625f : 1.0f;
  #pragma unroll
  for (int ni = 0; ni < 2; ++ni) {
    int col = N0 + wc * 64 + ni * 32 + ln31;
    float bb = Bv[col];
    #pragma unroll
    for (int mi = 0; mi < 2; ++mi)
      #pragma unroll
      for (int r = 0; r < 16; ++r) {
        int row = M0 + wr * 64 + mi * 32 + (r & 3) + ((r >> 2) << 3) + (lhalf << 2);
        Cb[(size_t)row * EMBED + col] = f2bf((acc[mi][ni][r] + bb) * sc);
      }
  }
}

// ---------------------------------------------------------------------------
// Output projection: split-bf16 3-term MFMA GEMM, double-buffered 2-phase.
// A (attn out, split 256B units) x Wo (split) + bo -> fp32 out.
// ---------------------------------------------------------------------------
__global__ __launch_bounds__(256) void gemm_out_split_k(
    const char* __restrict__ Apack, const char* __restrict__ Wpack,
    const float* __restrict__ Bv, float* __restrict__ Cf)
{
  __shared__ __align__(16) char Asm[32768];   // 2 x 16KB
  __shared__ __align__(16) char Wsm[32768];

  const int tid  = threadIdx.x;
  const int lane = tid & 63;
  const int wid  = tid >> 6;
  const int wr   = wid >> 1, wc = wid & 1;
  const int ln31 = lane & 31, lhalf = lane >> 5;

  const int bid = blockIdx.x;                 // 256 blocks
  const int swz = (bid & 7) * 32 + (bid >> 3);
  const int rp  = swz >> 3, cb = swz & 7;

  const int M0 = rp * 128, N0 = cb * 128;
  const int U0 = M0 >> 1, V0 = N0 >> 1;

  const char* ab[4]; const char* wb[4]; int ldoff[4];
  #pragma unroll
  for (int i = 0; i < 4; ++i) {
    int ul = i * 16 + (tid >> 4);
    int so = (tid & 15) << 4;
    ab[i] = Apack + ((size_t)(U0 + ul) << 13) + so;
    wb[i] = Wpack + ((size_t)(V0 + ul) << 13) + so;
    ldoff[i] = i * 4096 + (tid >> 6) * 1024;
  }

  f32x16 acc[2][2];
  #pragma unroll
  for (int mi = 0; mi < 2; ++mi)
    #pragma unroll
    for (int ni = 0; ni < 2; ++ni)
      #pragma unroll
      for (int q = 0; q < 16; ++q) acc[mi][ni][q] = 0.f;

  #pragma unroll
  for (int i = 0; i < 4; ++i) {
    async16(ab[i], &Asm[ldoff[i]]);
    async16(wb[i], &Wsm[ldoff[i]]);
  }
  __syncthreads();

  for (int t = 0; t < NKB; ++t) {
    const int c = t & 1;
    if (t + 1 < NKB) {
      #pragma unroll
      for (int i = 0; i < 4; ++i) {
        async16(ab[i] + ((t + 1) << 8), &Asm[(c ^ 1) * 16384 + ldoff[i]]);
        async16(wb[i] + ((t + 1) << 8), &Wsm[(c ^ 1) * 16384 + ldoff[i]]);
      }
    }
    const char* Ab = Asm + c * 16384;
    const char* Wb = Wsm + c * 16384;
    #pragma unroll
    for (int h = 0; h < 2; ++h) {
      const int kb = h * 2 + lhalf;
      bf8 aH[2], aL[2], bH[2], bL[2];
      #pragma unroll
      for (int mi = 0; mi < 2; ++mi) {
        int m = wr * 64 + mi * 32 + ln31;
        int u = m >> 1;
        int sH = (((m & 1) << 3) | kb) ^ (u & 15);
        aH[mi] = *(const bf8*)(Ab + u * 256 + sH * 16);
        aL[mi] = *(const bf8*)(Ab + u * 256 + (sH ^ 4) * 16);
      }
      #pragma unroll
      for (int ni = 0; ni < 2; ++ni) {
        int n = wc * 64 + ni * 32 + ln31;
        int u = n >> 1;
        int sH = (((n & 1) << 3) | kb) ^ (u & 15);
        bH[ni] = *(const bf8*)(Wb + u * 256 + sH * 16);
        bL[ni] = *(const bf8*)(Wb + u * 256 + (sH ^ 4) * 16);
      }
      #pragma unroll
      for (int mi = 0; mi < 2; ++mi)
        #pragma unroll
        for (int ni = 0; ni < 2; ++ni) {
          acc[mi][ni] = __builtin_amdgcn_mfma_f32_32x32x16_bf16(aH[mi], bH[ni], acc[mi][ni], 0, 0, 0);
          acc[mi][ni] = __builtin_amdgcn_mfma_f32_32x32x16_bf16(aH[mi], bL[ni], acc[mi][ni], 0, 0, 0);
          acc[mi][ni] = __builtin_amdgcn_mfma_f32_32x32x16_bf16(aL[mi], bH[ni], acc[mi][ni], 0, 0, 0);
        }
    }
    __syncthreads();
  }

  #pragma unroll
  for (int ni = 0; ni < 2; ++ni) {
    int col = N0 + wc * 64 + ni * 32 + ln31;
    float bb = Bv[col];
    #pragma unroll
    for (int mi = 0; mi < 2; ++mi)
      #pragma unroll
      for (int r = 0; r < 16; ++r) {
        int row = M0 + wr * 64 + mi * 32 + (r & 3) + ((r >> 2) << 3) + (lhalf << 2);
        Cf[(size_t)row * EMBED + col] = acc[mi][ni][r] + bb;
      }
  }
}

// ---------------------------------------------------------------------------
// MFMA flash attention, double-buffered K/V with T14 V-split.
// ---------------------------------------------------------------------------
__global__ __launch_bounds__(256) void attn_mfma_k(
    const unsigned short* __restrict__ Qb, const unsigned short* __restrict__ Kb,
    const unsigned short* __restrict__ Vb, char* __restrict__ A2)
{
  __shared__ __align__(16) char lds[32768];   // buf c: K @ c*16K, V^T @ c*16K+8K

  const int bid = blockIdx.x;
  const int swz = (bid & 7) * 64 + (bid >> 3);
  const int qt = swz & 15, h = (swz >> 4) & 15, b = swz >> 8;

  const int tid  = threadIdx.x;
  const int lane = tid & 63;
  const int w    = tid >> 6;
  const int ln31 = lane & 31, lh = lane >> 5;
  const int l7   = ln31 & 7;

  const int q0 = qt * 128;

  // Q fragments direct from global (pre-scaled by 1/64 in GEMM epilogue)
  bf8 qf[4];
  {
    const size_t qoff = (size_t)(b * SEQ + q0 + w * 32 + ln31) * EMBED + h * HDIM;
    #pragma unroll
    for (int kd = 0; kd < 4; ++kd)
      qf[kd] = *(const bf8*)(Qb + qoff + (2 * kd + lh) * 8);
  }

  // K staging addresses (pre-swizzled source, linear LDS dest)
  const unsigned short* ksrc[2]; int kldoff[2];
  #pragma unroll
  for (int i = 0; i < 2; ++i) {
    int idx = i * 256 + tid;
    int r = idx >> 3, s7 = idx & 7;
    int un = s7 ^ (r & 7);
    ksrc[i] = Kb + (size_t)(b * SEQ + r) * EMBED + h * HDIM + un * 8;
    kldoff[i] = i * 4096 + (tid >> 6) * 1024;
  }
  // V reg-staging addresses
  const int kp = tid & 31, d8 = (tid >> 5) << 3;
  const unsigned short* vsrc = Vb + (size_t)(b * SEQ + 2 * kp) * EMBED + h * HDIM + d8;

  us8 v0, v1;
  // prologue: stage tile 0
  #pragma unroll
  for (int i = 0; i < 2; ++i)
    async16(ksrc[i], lds + kldoff[i]);
  v0 = *(const us8*)(vsrc);
  v1 = *(const us8*)(vsrc + EMBED);
  #pragma unroll
  for (int j = 0; j < 8; ++j) {
    unsigned pr = (unsigned)v0[j] | ((unsigned)v1[j] << 16);
    int d = d8 + j;
    *(unsigned*)(lds + 8192 + d * 128 + (((kp >> 2) ^ (d & 7)) << 4) + ((kp & 3) << 2)) = pr;
  }
  __syncthreads();

  f32x16 oacc[2];
  #pragma unroll
  for (int df = 0; df < 2; ++df)
    #pragma unroll
    for (int r = 0; r < 16; ++r) oacc[df][r] = 0.f;
  float m_run = -1e30f, l_run = 0.f;

  for (int t = 0; t < NT; ++t) {
    const int c = t & 1;
    const int tn = (t + 1 < NT) ? t + 1 : t;   // clamped prefetch index
    // issue next-tile K -> LDS buf^1, V -> regs
    #pragma unroll
    for (int i = 0; i < 2; ++i)
      async16(ksrc[i] + (size_t)(tn * 64) * EMBED, lds + (c ^ 1) * 16384 + kldoff[i]);
    v0 = *(const us8*)(vsrc + (size_t)(tn * 64) * EMBED);
    v1 = *(const us8*)(vsrc + (size_t)(tn * 64) * EMBED + EMBED);

    // S^T = K * Q^T from buf c
    f32x16 sacc[2];
    #pragma unroll
    for (int kf = 0; kf < 2; ++kf)
      #pragma unroll
      for (int r = 0; r < 16; ++r) sacc[kf][r] = 0.f;
    __builtin_amdgcn_s_setprio(1);
    #pragma unroll
    for (int kf = 0; kf < 2; ++kf)
      #pragma unroll
      for (int kd = 0; kd < 4; ++kd) {
        bf8 ka = *(const bf8*)(lds + c * 16384 + (32 * kf + ln31) * 128 + (((2 * kd + lh) ^ l7) << 4));
        sacc[kf] = __builtin_amdgcn_mfma_f32_32x32x16_bf16(ka, qf[kd], sacc[kf], 0, 0, 0);
      }
    __builtin_amdgcn_s_setprio(0);

    // online softmax
    float mx = -1e30f;
    #pragma unroll
    for (int kf = 0; kf < 2; ++kf)
      #pragma unroll
      for (int r = 0; r < 16; ++r) mx = fmaxf(mx, sacc[kf][r]);
    mx = fmaxf(mx, __shfl_xor(mx, 32));
    float mnew = fmaxf(m_run, mx);
    float corr = __expf(m_run - mnew);
    float psum = 0.f;
    #pragma unroll
    for (int kf = 0; kf < 2; ++kf)
      #pragma unroll
      for (int r = 0; r < 16; ++r) {
        float p = __expf(sacc[kf][r] - mnew);
        sacc[kf][r] = p; psum += p;
      }
    psum += __shfl_xor(psum, 32);
    m_run = mnew;
    l_run = l_run * corr + psum;
    #pragma unroll
    for (int df = 0; df < 2; ++df)
      #pragma unroll
      for (int r = 0; r < 16; ++r) oacc[df][r] *= corr;

    // write next-tile V^T into buf^1 (vmcnt wait auto-inserted for v0/v1)
    #pragma unroll
    for (int j = 0; j < 8; ++j) {
      unsigned pr = (unsigned)v0[j] | ((unsigned)v1[j] << 16);
      int d = d8 + j;
      *(unsigned*)(lds + (c ^ 1) * 16384 + 8192 + d * 128 +
                   (((kp >> 2) ^ (d & 7)) << 4) + ((kp & 3) << 2)) = pr;
    }

    // pack P to bf16 pairs; partner exchange
    unsigned pk[2][8], sw[2][8];
    #pragma unroll
    for (int kf = 0; kf < 2; ++kf)
      #pragma unroll
      for (int g = 0; g < 4; ++g)
        #pragma unroll
        for (int j = 0; j < 2; ++j)
          pk[kf][2 * g + j] = (unsigned)f2bf(sacc[kf][4 * g + 2 * j]) |
                              ((unsigned)f2bf(sacc[kf][4 * g + 2 * j + 1]) << 16);
    #pragma unroll
    for (int kf = 0; kf < 2; ++kf)
      #pragma unroll
      for (int j = 0; j < 8; ++j)
        sw[kf][j] = (unsigned)__shfl_xor((int)pk[kf][j], 32);

    // O^T += V^T * P^T from buf c
    __builtin_amdgcn_s_setprio(1);
    #pragma unroll
    for (int kb = 0; kb < 4; ++kb) {
      const int kf = kb >> 1, b4 = (kb & 1) * 4;
      union { unsigned u[4]; bf8 v; } pf;
      pf.u[0] = lh ? sw[kf][b4 + 2] : pk[kf][b4 + 0];
      pf.u[1] = lh ? sw[kf][b4 + 3] : pk[kf][b4 + 1];
      pf.u[2] = lh ? pk[kf][b4 + 2] : sw[kf][b4 + 0];
      pf.u[3] = lh ? pk[kf][b4 + 3] : sw[kf][b4 + 1];
      #pragma unroll
      for (int df = 0; df < 2; ++df) {
        bf8 va = *(const bf8*)(lds + c * 16384 + 8192 + (32 * df + ln31) * 128 + (((2 * kb + lh) ^ l7) << 4));
        oacc[df] = __builtin_amdgcn_mfma_f32_32x32x16_bf16(va, pf.v, oacc[df], 0, 0, 0);
      }
    }
    __builtin_amdgcn_s_setprio(0);
    __syncthreads();
  }

  // epilogue: normalize, partner-exchange, write packed split-bf16
  const float inv = 1.0f / l_run;
  float own[8][4], swp[8][4];
  #pragma unroll
  for (int df = 0; df < 2; ++df)
    #pragma unroll
    for (int r = 0; r < 16; ++r)
      own[df * 4 + (r >> 2)][r & 3] = oacc[df][r] * inv;
  #pragma unroll
  for (int g = 0; g < 8; ++g)
    #pragma unroll
    for (int j = 0; j < 4; ++j)
      swp[g][j] = __shfl_xor(own[g][j], 32);

  const int row = b * SEQ + q0 + w * 32 + ln31;
  const int u = row >> 1, par = row & 1;
  #pragma unroll
  for (int g = 0; g < 8; ++g) {
    float f[8];
    #pragma unroll
    for (int e = 0; e < 8; ++e) {
      int j = e & 3;
      f[e] = (e < 4) ? (lh ? swp[g][j] : own[g][j])
                     : (lh ? own[g][j] : swp[g][j]);
    }
    us8 hi, lo;
    #pragma unroll
    for (int e = 0; e < 8; ++e) {
      unsigned short h8 = f2bf(f[e]);
      hi[e] = h8;
      lo[e] = f2bf(f[e] - bf2f(h8));
    }
    int t_blk = 2 * h + (g >> 2), kb8 = g & 3;
    size_t ub = ((size_t)(u * NKB + t_blk)) << 8;
    int sH = ((par << 3) | kb8) ^ (u & 15);
    *(us8*)(A2 + ub + (sH << 4)) = hi;
    *(us8*)(A2 + ub + ((sH ^ 4) << 4)) = lo;
  }
}

// ---------------------------------------------------------------------------
extern "C" void kernel_launch(void* const* d_in, const int* in_sizes, int n_in,
                              void* d_out, int out_size, void* d_ws, size_t ws_size,
                              hipStream_t stream)
{
  const float* x  = (const float*)d_in[0];
  const float* Wq = (const float*)d_in[1];
  const float* bq = (const float*)d_in[2];
  const float* Wk = (const float*)d_in[3];
  const float* bk = (const float*)d_in[4];
  const float* Wv = (const float*)d_in[5];
  const float* bv = (const float*)d_in[6];
  const float* Wo = (const float*)d_in[7];
  const float* bo = (const float*)d_in[8];
  float* out = (float*)d_out;

  char* wsb = (char*)d_ws;
  char*           Xp  = wsb;                                         // 8MB  bf16 x pack
  char*           Wp3 = wsb + ((size_t)8  << 20);                    // 6MB  bf16 Wq/Wk/Wv
  char*           Wos = wsb + ((size_t)14 << 20);                    // 4MB  split Wo
  unsigned short* Qbf = (unsigned short*)(wsb + ((size_t)18 << 20)); // 8MB
  unsigned short* Kbf = (unsigned short*)(wsb + ((size_t)26 << 20)); // 8MB
  unsigned short* Vbf = (unsigned short*)(wsb + ((size_t)34 << 20)); // 8MB
  char*           A2  = wsb + ((size_t)42 << 20);                    // 16MB split attn-out

  pack_x_bf16_k<<<dim3(2048), dim3(256), 0, stream>>>(x, Xp);
  pack_w_bf16_k<<<dim3(512, 3), dim3(256), 0, stream>>>(Wq, Wk, Wv, Wp3);
  pack_wo_split_k<<<dim3(1024), dim3(256), 0, stream>>>(Wo, Wos);

  gemm_qkv_bf16_k<<<dim3(768), dim3(256), 0, stream>>>(
      Xp, Wp3, bq, bk, bv, Qbf, Kbf, Vbf);

  attn_mfma_k<<<dim3(512), dim3(256), 0, stream>>>(Qbf, Kbf, Vbf, A2);

  gemm_out_split_k<<<dim3(256), dim3(256), 0, stream>>>(A2, Wos, bo, out);
}